// Round 1
// baseline (954.890 us; speedup 1.0000x reference)
//
#include <hip/hip_runtime.h>
#include <math.h>

// ---------------------------------------------------------------------------
// MMModel: 3-modality cross-attention block, f32 baseline implementation.
// Shapes: B=4, L=64, DM=1024, H=16, DK=DV=64, D=1024, DI=4096, nm=3.
// Row convention for all activation matrices: row = (i*B + b)*L + l  (768 rows)
// ---------------------------------------------------------------------------

#define NEGV (-1000000000.0f)

// ---------------- concat inputs into X[768][1024] ----------------
__global__ __launch_bounds__(256) void concat3(const float* __restrict__ t,
                                               const float* __restrict__ a,
                                               const float* __restrict__ v,
                                               float4* __restrict__ X) {
  int id = blockIdx.x * 256 + threadIdx.x;       // 768*256 = 196608 float4s
  int m = id >> 16;                              // 65536 float4 per modality
  int off = id & 65535;
  const float4* s = (m == 0) ? (const float4*)t : (m == 1) ? (const float4*)a
                                                           : (const float4*)v;
  X[id] = s[off];
}

// ---------------- generic f32 GEMM: C = A(MxK) * B(KxN) [+bias][+add][relu]
// 64x64 block tile, 256 threads, 4x4 microtile, K-chunk 16.
// grid = (N/64, M/64). lda/ldb = row strides. addsrc uses ldc.
__global__ __launch_bounds__(256) void gemm64(
    const float* __restrict__ A, int lda,
    const float* __restrict__ B, int ldb,
    float* __restrict__ C, int ldc, int K,
    const float* __restrict__ bias,
    const float* __restrict__ addsrc,
    int do_relu) {
  __shared__ float As[16][68];   // [k][m], padded: 68*4B = 272B row (16B aligned)
  __shared__ float Bs[16][68];   // [k][n]
  const int bm = blockIdx.y * 64;
  const int bn = blockIdx.x * 64;
  const int tid = threadIdx.x;
  const int tx = tid & 15, ty = tid >> 4;
  const int ar = tid >> 2, ac = (tid & 3) << 2;   // A tile: 64 rows x 16 k
  const int br = tid >> 4, bc = (tid & 15) << 2;  // B tile: 16 k x 64 cols
  float acc[4][4] = {};
  for (int k0 = 0; k0 < K; k0 += 16) {
    __syncthreads();
    float4 a4 = *(const float4*)(A + (size_t)(bm + ar) * lda + k0 + ac);
    float4 b4 = *(const float4*)(B + (size_t)(k0 + br) * ldb + bn + bc);
    As[ac + 0][ar] = a4.x; As[ac + 1][ar] = a4.y;
    As[ac + 2][ar] = a4.z; As[ac + 3][ar] = a4.w;
    *(float4*)&Bs[br][bc] = b4;
    __syncthreads();
#pragma unroll
    for (int kk = 0; kk < 16; ++kk) {
      float4 av = *(const float4*)&As[kk][ty * 4];
      float4 bv = *(const float4*)&Bs[kk][tx * 4];
      float aa[4] = {av.x, av.y, av.z, av.w};
      float bb[4] = {bv.x, bv.y, bv.z, bv.w};
#pragma unroll
      for (int i = 0; i < 4; ++i)
#pragma unroll
        for (int j = 0; j < 4; ++j)
          acc[i][j] = fmaf(aa[i], bb[j], acc[i][j]);
    }
  }
  float4 bias4;
  if (bias) bias4 = *(const float4*)(bias + bn + tx * 4);
  else { bias4.x = bias4.y = bias4.z = bias4.w = 0.f; }
#pragma unroll
  for (int i = 0; i < 4; ++i) {
    int row = bm + ty * 4 + i;
    float4 v;
    v.x = acc[i][0] + bias4.x; v.y = acc[i][1] + bias4.y;
    v.z = acc[i][2] + bias4.z; v.w = acc[i][3] + bias4.w;
    if (addsrc) {
      float4 r4 = *(const float4*)(addsrc + (size_t)row * ldc + bn + tx * 4);
      v.x += r4.x; v.y += r4.y; v.z += r4.z; v.w += r4.w;
    }
    if (do_relu) {
      v.x = fmaxf(v.x, 0.f); v.y = fmaxf(v.y, 0.f);
      v.z = fmaxf(v.z, 0.f); v.w = fmaxf(v.w, 0.f);
    }
    *(float4*)(C + (size_t)row * ldc + bn + tx * 4) = v;
  }
}

// ---------------- decision gate ----------------
// dec[i][j][b][q][k] = ( (Σ_d relu(A1[jb,q,d] + A0[ib,k,d]) * w2[d][1]) + b2[1]
//                      > (... * w2[d][0]) + b2[0] ) ? NEG : 0
// A1 already has dc_b1 folded in (GEMM bias). 32x32 pair tile, 2x2 per thread.
// grid = (4 tiles, B, 9 pairs), block 256.
__global__ __launch_bounds__(256) void decision_kernel(
    const float* __restrict__ A1, const float* __restrict__ A0,
    const float* __restrict__ w2, const float* __restrict__ b2,
    float* __restrict__ DEC) {
  __shared__ float sA1[32][132];
  __shared__ float sA0[32][132];
  __shared__ float sW2[128][2];
  const int b = blockIdx.y;
  const int p = blockIdx.z;          // p = i*3 + j
  const int i = p / 3, j = p % 3;
  const int qt = (blockIdx.x >> 1) * 32, kt = (blockIdx.x & 1) * 32;
  const int tid = threadIdx.x;
  const int tq = tid >> 4, tk = tid & 15;
  const float* a1base = A1 + ((size_t)(j * 4 + b) * 64 + qt) * 2048;
  const float* a0base = A0 + ((size_t)(i * 4 + b) * 64 + kt) * 2048;
  const int sr = tid >> 3, sc = (tid & 7) * 16;
  float acc[2][2][2] = {};
  for (int d0 = 0; d0 < 2048; d0 += 128) {
    __syncthreads();
#pragma unroll
    for (int t = 0; t < 4; ++t) {
      *(float4*)&sA1[sr][sc + t * 4] =
          *(const float4*)(a1base + (size_t)sr * 2048 + d0 + sc + t * 4);
      *(float4*)&sA0[sr][sc + t * 4] =
          *(const float4*)(a0base + (size_t)sr * 2048 + d0 + sc + t * 4);
    }
    if (tid < 128) {
      float2 w = *(const float2*)(w2 + (size_t)(d0 + tid) * 2);
      sW2[tid][0] = w.x; sW2[tid][1] = w.y;
    }
    __syncthreads();
    for (int dd = 0; dd < 128; ++dd) {
      float w0 = sW2[dd][0], w1 = sW2[dd][1];
      float x0 = sA1[tq * 2 + 0][dd], x1 = sA1[tq * 2 + 1][dd];
      float y0 = sA0[tk * 2 + 0][dd], y1 = sA0[tk * 2 + 1][dd];
      float v;
      v = fmaxf(x0 + y0, 0.f);
      acc[0][0][0] = fmaf(v, w0, acc[0][0][0]);
      acc[0][0][1] = fmaf(v, w1, acc[0][0][1]);
      v = fmaxf(x0 + y1, 0.f);
      acc[0][1][0] = fmaf(v, w0, acc[0][1][0]);
      acc[0][1][1] = fmaf(v, w1, acc[0][1][1]);
      v = fmaxf(x1 + y0, 0.f);
      acc[1][0][0] = fmaf(v, w0, acc[1][0][0]);
      acc[1][0][1] = fmaf(v, w1, acc[1][0][1]);
      v = fmaxf(x1 + y1, 0.f);
      acc[1][1][0] = fmaf(v, w0, acc[1][1][0]);
      acc[1][1][1] = fmaf(v, w1, acc[1][1][1]);
    }
  }
  float b20 = b2[0], b21 = b2[1];
  float* out = DEC + ((size_t)p * 4 + b) * 4096;
#pragma unroll
  for (int dq = 0; dq < 2; ++dq)
#pragma unroll
    for (int dk = 0; dk < 2; ++dk) {
      float l0 = acc[dq][dk][0] + b20;
      float l1 = acc[dq][dk][1] + b21;
      int q = qt + tq * 2 + dq, k = kt + tk * 2 + dk;
      out[q * 64 + k] = (l1 > l0) ? NEGV : 0.f;
    }
}

// ---------------- attention ----------------
// grid = (H, B, nm), block 256. Per wg: queries of modality i, batch b, head h.
// Two halves of 32 query rows; 192 keys (3 modalities x 64).
__global__ __launch_bounds__(256) void attn_kernel(
    const float* __restrict__ Qa, const float* __restrict__ Ka,
    const float* __restrict__ Va, const float* __restrict__ DEC,
    const int* __restrict__ mask, float* __restrict__ O) {
  __shared__ float Qs[32][68];
  __shared__ float Ks[32][68];
  __shared__ float S[32][193];
  __shared__ float red[32][10];
  const int h = blockIdx.x, b = blockIdx.y, i = blockIdx.z;
  const int tid = threadIdx.x;
  for (int half = 0; half < 2; ++half) {
    const int qbase = half * 32;
    {
      int r = tid >> 3, c = (tid & 7) * 8;
      const float* src =
          Qa + (((size_t)(i * 4 + b) * 64 + qbase + r) * 1024) + h * 64 + c;
      *(float4*)&Qs[r][c] = *(const float4*)src;
      *(float4*)&Qs[r][c + 4] = *(const float4*)(src + 4);
    }
    // ---- scores ----
    for (int jc = 0; jc < 6; ++jc) {
      int j = jc >> 1, kb = (jc & 1) * 32;
      __syncthreads();
      {
        int r = tid >> 3, c = (tid & 7) * 8;
        const float* src =
            Ka + (((size_t)(j * 4 + b) * 64 + kb + r) * 1024) + h * 64 + c;
        *(float4*)&Ks[r][c] = *(const float4*)src;
        *(float4*)&Ks[r][c + 4] = *(const float4*)(src + 4);
      }
      __syncthreads();
      int q = tid >> 3, k0 = (tid & 7) * 4;
#pragma unroll
      for (int m = 0; m < 4; ++m) {
        int kl = k0 + m;
        int l = kb + kl;
        float s = 0.f;
#pragma unroll
        for (int d4 = 0; d4 < 16; ++d4) {
          float4 qv = *(const float4*)&Qs[q][d4 * 4];
          float4 kv = *(const float4*)&Ks[kl][d4 * 4];
          s = fmaf(qv.x, kv.x, s); s = fmaf(qv.y, kv.y, s);
          s = fmaf(qv.z, kv.z, s); s = fmaf(qv.w, kv.w, s);
        }
        s *= 0.125f;  // / sqrt(DK)
        int qg = qbase + q;
        s += DEC[(((size_t)(i * 3 + j) * 4 + b) * 4096) + qg * 64 + l];
        if (mask[((size_t)b * 64 + qg) * 64 + l] == 0) s = NEGV;
        S[q][j * 64 + l] = s;
      }
    }
    __syncthreads();
    // ---- softmax over 192 keys ----
    int q = tid >> 3, sub = tid & 7;
    float mx = -3.0e38f;
    for (int kk = sub; kk < 192; kk += 8) mx = fmaxf(mx, S[q][kk]);
    red[q][sub] = mx;
    __syncthreads();
    if (sub == 0) {
      float m2 = red[q][0];
#pragma unroll
      for (int t = 1; t < 8; ++t) m2 = fmaxf(m2, red[q][t]);
      red[q][8] = m2;
    }
    __syncthreads();
    mx = red[q][8];
    float sum = 0.f;
    for (int kk = sub; kk < 192; kk += 8) {
      float pp = __expf(S[q][kk] - mx);
      S[q][kk] = pp;
      sum += pp;
    }
    red[q][sub] = sum;
    __syncthreads();
    if (sub == 0) {
      float s2 = 0.f;
#pragma unroll
      for (int t = 0; t < 8; ++t) s2 += red[q][t];
      red[q][9] = s2;
    }
    __syncthreads();
    float inv = 1.0f / red[q][9];
    // ---- A @ V ----
    float acc[8] = {};
    for (int kk = 0; kk < 192; ++kk) {
      int j = kk >> 6, l = kk & 63;
      const float* vp =
          Va + (((size_t)(j * 4 + b) * 64 + l) * 1024) + h * 64 + sub * 8;
      float pw = S[q][kk];
      float4 v0 = *(const float4*)vp;
      float4 v1 = *(const float4*)(vp + 4);
      acc[0] = fmaf(pw, v0.x, acc[0]); acc[1] = fmaf(pw, v0.y, acc[1]);
      acc[2] = fmaf(pw, v0.z, acc[2]); acc[3] = fmaf(pw, v0.w, acc[3]);
      acc[4] = fmaf(pw, v1.x, acc[4]); acc[5] = fmaf(pw, v1.y, acc[5]);
      acc[6] = fmaf(pw, v1.z, acc[6]); acc[7] = fmaf(pw, v1.w, acc[7]);
    }
    float* op =
        O + (((size_t)(i * 4 + b) * 64 + qbase + q) * 1024) + h * 64 + sub * 8;
    float4 o0, o1;
    o0.x = acc[0] * inv; o0.y = acc[1] * inv;
    o0.z = acc[2] * inv; o0.w = acc[3] * inv;
    o1.x = acc[4] * inv; o1.y = acc[5] * inv;
    o1.z = acc[6] * inv; o1.w = acc[7] * inv;
    *(float4*)op = o0;
    *(float4*)(op + 4) = o1;
    __syncthreads();  // protect Qs/S/red before next half
  }
}

// ---------------- layer norm over rows of 1024 ----------------
__global__ __launch_bounds__(256) void ln_kernel(const float* __restrict__ X,
                                                 const float* __restrict__ g,
                                                 const float* __restrict__ be,
                                                 float* __restrict__ Y) {
  __shared__ float rs[8];
  int row = blockIdx.x, tid = threadIdx.x;
  const float* x = X + (size_t)row * 1024 + tid * 4;
  float4 v = *(const float4*)x;
  float s = v.x + v.y + v.z + v.w;
  float s2 = v.x * v.x + v.y * v.y + v.z * v.z + v.w * v.w;
#pragma unroll
  for (int off = 32; off > 0; off >>= 1) {
    s += __shfl_down(s, off);
    s2 += __shfl_down(s2, off);
  }
  int lane = tid & 63, wid = tid >> 6;
  if (lane == 0) { rs[wid * 2] = s; rs[wid * 2 + 1] = s2; }
  __syncthreads();
  if (tid == 0) {
    float a = rs[0] + rs[2] + rs[4] + rs[6];
    float c = rs[1] + rs[3] + rs[5] + rs[7];
    rs[0] = a; rs[1] = c;
  }
  __syncthreads();
  float mu = rs[0] * (1.0f / 1024.0f);
  float var = rs[1] * (1.0f / 1024.0f) - mu * mu;
  var = fmaxf(var, 0.f);
  float inv = 1.0f / sqrtf(var + 1e-6f);
  float4 gv = *(const float4*)(g + tid * 4);
  float4 bv = *(const float4*)(be + tid * 4);
  float4 o;
  o.x = (v.x - mu) * inv * gv.x + bv.x;
  o.y = (v.y - mu) * inv * gv.y + bv.y;
  o.z = (v.z - mu) * inv * gv.z + bv.z;
  o.w = (v.w - mu) * inv * gv.w + bv.w;
  *(float4*)(Y + (size_t)row * 1024 + tid * 4) = o;
}

// ---------------------------------------------------------------------------
extern "C" void kernel_launch(void* const* d_in, const int* in_sizes, int n_in,
                              void* d_out, int out_size, void* d_ws,
                              size_t ws_size, hipStream_t stream) {
  const float* in_t = (const float*)d_in[0];
  const float* in_a = (const float*)d_in[1];
  const float* in_v = (const float*)d_in[2];
  const int* mask = (const int*)d_in[3];
  const float* w_qs = (const float*)d_in[4];
  const float* w_ks = (const float*)d_in[5];
  const float* w_vs = (const float*)d_in[6];
  const float* w_ds0 = (const float*)d_in[7];
  const float* w_ds1 = (const float*)d_in[8];
  const float* dc_w1 = (const float*)d_in[9];
  const float* dc_b1 = (const float*)d_in[10];
  const float* dc_w2 = (const float*)d_in[11];
  const float* dc_b2 = (const float*)d_in[12];
  const float* w_fc = (const float*)d_in[13];
  const float* ln1_g = (const float*)d_in[14];
  const float* ln1_b = (const float*)d_in[15];
  const float* ffn_w1 = (const float*)d_in[16];
  const float* ffn_b1 = (const float*)d_in[17];
  const float* ffn_w2 = (const float*)d_in[18];
  const float* ffn_b2 = (const float*)d_in[19];
  const float* ln2_g = (const float*)d_in[20];
  const float* ln2_b = (const float*)d_in[21];
  float* out = (float*)d_out;

  // workspace layout (floats); total 13,516,800 floats = 51.6 MiB
  float* ws = (float*)d_ws;
  float* X = ws;                    // 768x1024
  float* Qa = X + 786432;           // 768x1024
  float* Ka = Qa + 786432;          // 768x1024
  float* Va = Ka + 786432;          // 768x1024
  float* D0 = Va + 786432;          // 768x1024
  float* D1 = D0 + 786432;          // 768x1024
  float* A0 = D1 + 786432;          // 768x2048
  float* A1 = A0 + 1572864;         // 768x2048 (dc_b1 folded)
  float* DEC = A1 + 1572864;        // 9x4x64x64
  float* OATT = DEC + 147456;       // 768x1024
  float* O1 = OATT + 786432;        // 768x1024 (LN1 out)
  float* Hf = O1 + 786432;          // 768x4096
  float* F2 = Hf + 3145728;         // 768x1024 (temp)

  dim3 blk(256);
  concat3<<<dim3(768), blk, 0, stream>>>(in_t, in_a, in_v, (float4*)X);

  dim3 g1(1024 / 64, 768 / 64);   // N=1024
  gemm64<<<g1, blk, 0, stream>>>(X, 1024, w_qs, 1024, Qa, 1024, 1024, nullptr, nullptr, 0);
  gemm64<<<g1, blk, 0, stream>>>(X, 1024, w_ks, 1024, Ka, 1024, 1024, nullptr, nullptr, 0);
  gemm64<<<g1, blk, 0, stream>>>(X, 1024, w_vs, 1024, Va, 1024, 1024, nullptr, nullptr, 0);
  gemm64<<<g1, blk, 0, stream>>>(X, 1024, w_ds0, 1024, D0, 1024, 1024, nullptr, nullptr, 0);
  gemm64<<<g1, blk, 0, stream>>>(X, 1024, w_ds1, 1024, D1, 1024, 1024, nullptr, nullptr, 0);

  dim3 g2(2048 / 64, 768 / 64);   // N=2048
  // a0 = d0 @ dc_w1[D:]   (rows 1024..2047 of dc_w1)
  gemm64<<<g2, blk, 0, stream>>>(D0, 1024, dc_w1 + (size_t)1024 * 2048, 2048,
                                 A0, 2048, 1024, nullptr, nullptr, 0);
  // a1 = d1 @ dc_w1[:D] + dc_b1  (bias folded here)
  gemm64<<<g2, blk, 0, stream>>>(D1, 1024, dc_w1, 2048, A1, 2048, 1024, dc_b1,
                                 nullptr, 0);

  decision_kernel<<<dim3(4, 4, 9), blk, 0, stream>>>(A1, A0, dc_w2, dc_b2, DEC);

  attn_kernel<<<dim3(16, 4, 3), blk, 0, stream>>>(Qa, Ka, Va, DEC, mask, OATT);

  // o @ w_fc + residual(X) -> F2 ; LN1 -> O1
  gemm64<<<g1, blk, 0, stream>>>(OATT, 1024, w_fc, 1024, F2, 1024, 1024,
                                 nullptr, X, 0);
  ln_kernel<<<dim3(768), blk, 0, stream>>>(F2, ln1_g, ln1_b, O1);

  // FFN
  dim3 g3(4096 / 64, 768 / 64);
  gemm64<<<g3, blk, 0, stream>>>(O1, 1024, ffn_w1, 4096, Hf, 4096, 1024,
                                 ffn_b1, nullptr, 1);
  gemm64<<<g1, blk, 0, stream>>>(Hf, 4096, ffn_w2, 1024, F2, 1024, 4096,
                                 ffn_b2, O1, 0);
  ln_kernel<<<dim3(768), blk, 0, stream>>>(F2, ln2_g, ln2_b, out);
}

// Round 2
// 304.365 us; speedup vs baseline: 3.1373x; 3.1373x over previous
//
#include <hip/hip_runtime.h>
#include <math.h>

// ---------------------------------------------------------------------------
// MMModel bf16-MFMA implementation. B=4, L=64, DM=1024, H=16, DK=DV=64,
// D=1024, DI=4096, nm=3. Row convention: row = (i*B + b)*L + l  (768 rows).
// ---------------------------------------------------------------------------

#define NEGV (-1000000000.0f)

typedef float f32x4 __attribute__((ext_vector_type(4)));
typedef short short8 __attribute__((ext_vector_type(8)));
typedef unsigned short u16x8 __attribute__((ext_vector_type(8)));
typedef unsigned short u16x4 __attribute__((ext_vector_type(4)));

static __device__ __forceinline__ unsigned short f2bf(float f) {
  unsigned u = __builtin_bit_cast(unsigned, f);
  u += 0x7fffu + ((u >> 16) & 1u);
  return (unsigned short)(u >> 16);
}
static __device__ __forceinline__ float bf2f(unsigned short h) {
  return __builtin_bit_cast(float, ((unsigned)h) << 16);
}

// ---------------- concat inputs into Xf[768][1024] f32 + Xb bf16 ------------
__global__ __launch_bounds__(256) void concat3(const float4* __restrict__ t,
                                               const float4* __restrict__ a,
                                               const float4* __restrict__ v,
                                               float4* __restrict__ Xf,
                                               u16x4* __restrict__ Xb) {
  int id = blockIdx.x * 256 + threadIdx.x;  // 768*256 float4s
  int m = id >> 16;
  int off = id & 65535;
  const float4* s = (m == 0) ? t : (m == 1) ? a : v;
  float4 val = s[off];
  Xf[id] = val;
  u16x4 bb;
  bb.x = f2bf(val.x); bb.y = f2bf(val.y);
  bb.z = f2bf(val.z); bb.w = f2bf(val.w);
  Xb[id] = bb;
}

// ---------------- weight transpose + f32->bf16: dst[n][k] = src[k][n] -------
struct WtJob { const float* src; unsigned short* dst; int K, N, tstart; };
struct WtJobs { WtJob j[9]; };

__global__ __launch_bounds__(256) void wt_transpose(WtJobs jobs) {
  __shared__ float Ls[32][33];
  int ji = 0;
#pragma unroll
  for (int t = 1; t < 9; ++t)
    if ((int)blockIdx.x >= jobs.j[t].tstart) ji = t;
  const WtJob jb = jobs.j[ji];
  int local = blockIdx.x - jb.tstart;
  int ntx = jb.N >> 5;
  int tk = local / ntx, tn = local - tk * ntx;
  const int tid = threadIdx.x;
  const int r = tid >> 3, c = (tid & 7) * 4;
  float4 v = *(const float4*)(jb.src + (size_t)(tk * 32 + r) * jb.N + tn * 32 + c);
  Ls[r][c + 0] = v.x; Ls[r][c + 1] = v.y;
  Ls[r][c + 2] = v.z; Ls[r][c + 3] = v.w;
  __syncthreads();
  u16x4 o;
  o.x = f2bf(Ls[c + 0][r]);
  o.y = f2bf(Ls[c + 1][r]);
  o.z = f2bf(Ls[c + 2][r]);
  o.w = f2bf(Ls[c + 3][r]);
  *(u16x4*)(jb.dst + (size_t)(tn * 32 + r) * jb.K + tk * 32 + c) = o;
}

// ---------------- bf16 MFMA GEMM -------------------------------------------
// C[M=768][N] = A[768][K](bf16) * Wt[N][K](bf16)^T  (+bias)(+add f32)(relu)
// outputs: Cf (f32) and/or Cb (bf16). 64x64 tile, 4 waves, 32x32 per wave.
struct GemmOp {
  const unsigned short* A;
  const unsigned short* B;   // Wt, row n, col k, stride ldb
  const float* bias;         // [N] or null
  const float* add;          // [768][N] f32 or null
  float* Cf;                 // or null
  unsigned short* Cb;        // or null
  int lda, ldb, N, K, relu;
};
struct GemmBatch { GemmOp op[5]; };

__global__ __launch_bounds__(256, 2) void gemm_mfma(GemmBatch batch) {
  const GemmOp g = batch.op[blockIdx.z];
  __shared__ unsigned short As[64][72];  // [m][k], 144B row stride (16B mult)
  __shared__ unsigned short Bs[64][72];  // [n][k]
  const int bm = blockIdx.y * 64, bn = blockIdx.x * 64;
  const int tid = threadIdx.x;
  const int l = tid & 63, w = tid >> 6;
  const int wr = (w >> 1) * 32, wc = (w & 1) * 32;  // wave quadrant
  const int lr = l & 15, lg = l >> 4;               // frag row/col, k-group
  const int sr = tid >> 2, sc = (tid & 3) * 16;     // staging coords
  f32x4 acc[2][2] = {};
  const unsigned short* ap = g.A + (size_t)(bm + sr) * g.lda + sc;
  const unsigned short* bp = g.B + (size_t)(bn + sr) * g.ldb + sc;
  for (int k0 = 0; k0 < g.K; k0 += 64) {
    __syncthreads();
    u16x8 av0 = *(const u16x8*)(ap + k0);
    u16x8 av1 = *(const u16x8*)(ap + k0 + 8);
    u16x8 bv0 = *(const u16x8*)(bp + k0);
    u16x8 bv1 = *(const u16x8*)(bp + k0 + 8);
    *(u16x8*)&As[sr][sc] = av0;
    *(u16x8*)&As[sr][sc + 8] = av1;
    *(u16x8*)&Bs[sr][sc] = bv0;
    *(u16x8*)&Bs[sr][sc + 8] = bv1;
    __syncthreads();
#pragma unroll
    for (int kk = 0; kk < 64; kk += 32) {
      short8 af0 = *(const short8*)&As[wr + 0 + lr][kk + lg * 8];
      short8 af1 = *(const short8*)&As[wr + 16 + lr][kk + lg * 8];
      short8 bf0 = *(const short8*)&Bs[wc + 0 + lr][kk + lg * 8];
      short8 bf1 = *(const short8*)&Bs[wc + 16 + lr][kk + lg * 8];
      acc[0][0] = __builtin_amdgcn_mfma_f32_16x16x32_bf16(af0, bf0, acc[0][0], 0, 0, 0);
      acc[0][1] = __builtin_amdgcn_mfma_f32_16x16x32_bf16(af0, bf1, acc[0][1], 0, 0, 0);
      acc[1][0] = __builtin_amdgcn_mfma_f32_16x16x32_bf16(af1, bf0, acc[1][0], 0, 0, 0);
      acc[1][1] = __builtin_amdgcn_mfma_f32_16x16x32_bf16(af1, bf1, acc[1][1], 0, 0, 0);
    }
  }
  // epilogue: C/D layout col=lane&15, row=(lane>>4)*4+reg   [m89 verified]
#pragma unroll
  for (int n = 0; n < 2; ++n) {
    const int col = bn + wc + n * 16 + lr;
    const float bv = g.bias ? g.bias[col] : 0.0f;
#pragma unroll
    for (int m = 0; m < 2; ++m) {
#pragma unroll
      for (int ii = 0; ii < 4; ++ii) {
        const int row = bm + wr + m * 16 + lg * 4 + ii;
        float v = acc[m][n][ii] + bv;
        if (g.add) v += g.add[(size_t)row * g.N + col];
        if (g.relu) v = fmaxf(v, 0.0f);
        if (g.Cf) g.Cf[(size_t)row * g.N + col] = v;
        if (g.Cb) g.Cb[(size_t)row * g.N + col] = f2bf(v);
      }
    }
  }
}

// ---------------- decision gate (16x16 pair tiles, 576 blocks) --------------
// dec[p=i*3+j][b][q][k]: logits_c = sum_d relu(A1[jb,q,d]+A0[ib,k,d])*w2[d][c]
// A1 has dc_b1 folded. grid = (16, B, 9), block 256 (one pair per thread).
__global__ __launch_bounds__(256) void decision_kernel(
    const float* __restrict__ A1, const float* __restrict__ A0,
    const float* __restrict__ w2, const float* __restrict__ b2,
    float* __restrict__ DEC) {
  __shared__ float sA1[16][132];
  __shared__ float sA0[16][132];
  __shared__ float sW2[128][2];
  const int b = blockIdx.y;
  const int p = blockIdx.z;
  const int i = p / 3, j = p % 3;
  const int qt = (blockIdx.x >> 2) * 16, kt = (blockIdx.x & 3) * 16;
  const int tid = threadIdx.x;
  const int tq = tid >> 4, tk = tid & 15;
  const float* a1base = A1 + ((size_t)(j * 4 + b) * 64 + qt) * 2048;
  const float* a0base = A0 + ((size_t)(i * 4 + b) * 64 + kt) * 2048;
  const int sr = tid >> 4, sc2 = (tid & 15) * 8;
  float acc0 = 0.f, acc1 = 0.f;
  for (int d0 = 0; d0 < 2048; d0 += 128) {
    __syncthreads();
    *(float4*)&sA1[sr][sc2] = *(const float4*)(a1base + (size_t)sr * 2048 + d0 + sc2);
    *(float4*)&sA1[sr][sc2 + 4] = *(const float4*)(a1base + (size_t)sr * 2048 + d0 + sc2 + 4);
    *(float4*)&sA0[sr][sc2] = *(const float4*)(a0base + (size_t)sr * 2048 + d0 + sc2);
    *(float4*)&sA0[sr][sc2 + 4] = *(const float4*)(a0base + (size_t)sr * 2048 + d0 + sc2 + 4);
    if (tid < 128) {
      float2 wv = *(const float2*)(w2 + (size_t)(d0 + tid) * 2);
      sW2[tid][0] = wv.x; sW2[tid][1] = wv.y;
    }
    __syncthreads();
#pragma unroll 8
    for (int dd = 0; dd < 128; ++dd) {
      float v = fmaxf(sA1[tq][dd] + sA0[tk][dd], 0.f);
      acc0 = fmaf(v, sW2[dd][0], acc0);
      acc1 = fmaf(v, sW2[dd][1], acc1);
    }
  }
  float l0 = acc0 + b2[0], l1 = acc1 + b2[1];
  DEC[((size_t)p * 4 + b) * 4096 + (qt + tq) * 64 + kt + tk] =
      (l1 > l0) ? NEGV : 0.f;
}

// ---------------- attention (bf16 Q/K/V in, bf16 O out) ---------------------
// grid = (H, B, nm), block 256.
__global__ __launch_bounds__(256) void attn_kernel(
    const unsigned short* __restrict__ Qa, const unsigned short* __restrict__ Ka,
    const unsigned short* __restrict__ Va, const float* __restrict__ DEC,
    const int* __restrict__ mask, unsigned short* __restrict__ O) {
  __shared__ float Qs[32][68];
  __shared__ float Ks[32][68];
  __shared__ float S[32][193];
  __shared__ float red[32][10];
  const int h = blockIdx.x, b = blockIdx.y, i = blockIdx.z;
  const int tid = threadIdx.x;
  for (int half = 0; half < 2; ++half) {
    const int qbase = half * 32;
    {
      int r = tid >> 3, c = (tid & 7) * 8;
      const unsigned short* src =
          Qa + (((size_t)(i * 4 + b) * 64 + qbase + r) * 1024) + h * 64 + c;
      u16x8 qv = *(const u16x8*)src;
#pragma unroll
      for (int jj = 0; jj < 8; ++jj) Qs[r][c + jj] = bf2f(qv[jj]);
    }
    // ---- scores ----
    for (int jc = 0; jc < 6; ++jc) {
      int j = jc >> 1, kb = (jc & 1) * 32;
      __syncthreads();
      {
        int r = tid >> 3, c = (tid & 7) * 8;
        const unsigned short* src =
            Ka + (((size_t)(j * 4 + b) * 64 + kb + r) * 1024) + h * 64 + c;
        u16x8 kv = *(const u16x8*)src;
#pragma unroll
        for (int jj = 0; jj < 8; ++jj) Ks[r][c + jj] = bf2f(kv[jj]);
      }
      __syncthreads();
      int q = tid >> 3, k0 = (tid & 7) * 4;
#pragma unroll
      for (int m = 0; m < 4; ++m) {
        int kl = k0 + m;
        int lkey = kb + kl;
        float s = 0.f;
#pragma unroll
        for (int d4 = 0; d4 < 16; ++d4) {
          float4 qv = *(const float4*)&Qs[q][d4 * 4];
          float4 kv = *(const float4*)&Ks[kl][d4 * 4];
          s = fmaf(qv.x, kv.x, s); s = fmaf(qv.y, kv.y, s);
          s = fmaf(qv.z, kv.z, s); s = fmaf(qv.w, kv.w, s);
        }
        s *= 0.125f;
        int qg = qbase + q;
        s += DEC[(((size_t)(i * 3 + j) * 4 + b) * 4096) + qg * 64 + lkey];
        if (mask[((size_t)b * 64 + qg) * 64 + lkey] == 0) s = NEGV;
        S[q][j * 64 + lkey] = s;
      }
    }
    __syncthreads();
    // ---- softmax over 192 keys ----
    int q = tid >> 3, sub = tid & 7;
    float mx = -3.0e38f;
    for (int kk = sub; kk < 192; kk += 8) mx = fmaxf(mx, S[q][kk]);
    red[q][sub] = mx;
    __syncthreads();
    if (sub == 0) {
      float m2 = red[q][0];
#pragma unroll
      for (int t = 1; t < 8; ++t) m2 = fmaxf(m2, red[q][t]);
      red[q][8] = m2;
    }
    __syncthreads();
    mx = red[q][8];
    float sum = 0.f;
    for (int kk = sub; kk < 192; kk += 8) {
      float pp = __expf(S[q][kk] - mx);
      S[q][kk] = pp;
      sum += pp;
    }
    red[q][sub] = sum;
    __syncthreads();
    if (sub == 0) {
      float s2 = 0.f;
#pragma unroll
      for (int t = 0; t < 8; ++t) s2 += red[q][t];
      red[q][9] = s2;
    }
    __syncthreads();
    float inv = 1.0f / red[q][9];
    // ---- A @ V ----
    float acc[8] = {};
    for (int kk = 0; kk < 192; ++kk) {
      int j = kk >> 6, lkey = kk & 63;
      const unsigned short* vp =
          Va + (((size_t)(j * 4 + b) * 64 + lkey) * 1024) + h * 64 + sub * 8;
      float pw = S[q][kk];
      u16x8 vv = *(const u16x8*)vp;
#pragma unroll
      for (int jj = 0; jj < 8; ++jj) acc[jj] = fmaf(pw, bf2f(vv[jj]), acc[jj]);
    }
    u16x8 ov;
#pragma unroll
    for (int jj = 0; jj < 8; ++jj) ov[jj] = f2bf(acc[jj] * inv);
    *(u16x8*)(O + (((size_t)(i * 4 + b) * 64 + qbase + q) * 1024) + h * 64 +
              sub * 8) = ov;
    __syncthreads();
  }
}

// ---------------- layer norm over rows of 1024 ------------------------------
__global__ __launch_bounds__(256) void ln_kernel(const float* __restrict__ X,
                                                 const float* __restrict__ g,
                                                 const float* __restrict__ be,
                                                 float* __restrict__ Y,
                                                 unsigned short* __restrict__ Yb) {
  __shared__ float rs[8];
  int row = blockIdx.x, tid = threadIdx.x;
  const float* x = X + (size_t)row * 1024 + tid * 4;
  float4 v = *(const float4*)x;
  float s = v.x + v.y + v.z + v.w;
  float s2 = v.x * v.x + v.y * v.y + v.z * v.z + v.w * v.w;
#pragma unroll
  for (int off = 32; off > 0; off >>= 1) {
    s += __shfl_down(s, off);
    s2 += __shfl_down(s2, off);
  }
  int lane = tid & 63, wid = tid >> 6;
  if (lane == 0) { rs[wid * 2] = s; rs[wid * 2 + 1] = s2; }
  __syncthreads();
  if (tid == 0) {
    float aa = rs[0] + rs[2] + rs[4] + rs[6];
    float cc = rs[1] + rs[3] + rs[5] + rs[7];
    rs[0] = aa; rs[1] = cc;
  }
  __syncthreads();
  float mu = rs[0] * (1.0f / 1024.0f);
  float var = rs[1] * (1.0f / 1024.0f) - mu * mu;
  var = fmaxf(var, 0.f);
  float inv = 1.0f / sqrtf(var + 1e-6f);
  float4 gv = *(const float4*)(g + tid * 4);
  float4 bv = *(const float4*)(be + tid * 4);
  float4 o;
  o.x = (v.x - mu) * inv * gv.x + bv.x;
  o.y = (v.y - mu) * inv * gv.y + bv.y;
  o.z = (v.z - mu) * inv * gv.z + bv.z;
  o.w = (v.w - mu) * inv * gv.w + bv.w;
  *(float4*)(Y + (size_t)row * 1024 + tid * 4) = o;
  if (Yb) {
    u16x4 ob;
    ob.x = f2bf(o.x); ob.y = f2bf(o.y); ob.z = f2bf(o.z); ob.w = f2bf(o.w);
    *(u16x4*)(Yb + (size_t)row * 1024 + tid * 4) = ob;
  }
}

// ---------------------------------------------------------------------------
extern "C" void kernel_launch(void* const* d_in, const int* in_sizes, int n_in,
                              void* d_out, int out_size, void* d_ws,
                              size_t ws_size, hipStream_t stream) {
  const float* in_t = (const float*)d_in[0];
  const float* in_a = (const float*)d_in[1];
  const float* in_v = (const float*)d_in[2];
  const int* mask = (const int*)d_in[3];
  const float* w_qs = (const float*)d_in[4];
  const float* w_ks = (const float*)d_in[5];
  const float* w_vs = (const float*)d_in[6];
  const float* w_ds0 = (const float*)d_in[7];
  const float* w_ds1 = (const float*)d_in[8];
  const float* dc_w1 = (const float*)d_in[9];
  const float* dc_b1 = (const float*)d_in[10];
  const float* dc_w2 = (const float*)d_in[11];
  const float* dc_b2 = (const float*)d_in[12];
  const float* w_fc = (const float*)d_in[13];
  const float* ln1_g = (const float*)d_in[14];
  const float* ln1_b = (const float*)d_in[15];
  const float* ffn_w1 = (const float*)d_in[16];
  const float* ffn_b1 = (const float*)d_in[17];
  const float* ffn_w2 = (const float*)d_in[18];
  const float* ffn_b2 = (const float*)d_in[19];
  const float* ln2_g = (const float*)d_in[20];
  const float* ln2_b = (const float*)d_in[21];
  float* out = (float*)d_out;

  // ---- workspace layout (bytes, 256-aligned) ----
  char* p = (char*)d_ws;
  auto alloc = [&](size_t bytes) {
    char* r = p;
    p += (bytes + 255) & ~(size_t)255;
    return r;
  };
  unsigned short* WQS = (unsigned short*)alloc(1024 * 1024 * 2);
  unsigned short* WKS = (unsigned short*)alloc(1024 * 1024 * 2);
  unsigned short* WVS = (unsigned short*)alloc(1024 * 1024 * 2);
  unsigned short* WD0 = (unsigned short*)alloc(1024 * 1024 * 2);
  unsigned short* WD1 = (unsigned short*)alloc(1024 * 1024 * 2);
  unsigned short* WW1 = (unsigned short*)alloc((size_t)2048 * 2048 * 2);
  unsigned short* WFC = (unsigned short*)alloc(1024 * 1024 * 2);
  unsigned short* WF1 = (unsigned short*)alloc((size_t)4096 * 1024 * 2);
  unsigned short* WF2 = (unsigned short*)alloc((size_t)1024 * 4096 * 2);
  float* Xf = (float*)alloc((size_t)786432 * 4);
  unsigned short* Xb = (unsigned short*)alloc((size_t)786432 * 2);
  unsigned short* Qb = (unsigned short*)alloc((size_t)786432 * 2);
  unsigned short* Kb = (unsigned short*)alloc((size_t)786432 * 2);
  unsigned short* Vb = (unsigned short*)alloc((size_t)786432 * 2);
  unsigned short* D0b = (unsigned short*)alloc((size_t)786432 * 2);
  unsigned short* D1b = (unsigned short*)alloc((size_t)786432 * 2);
  float* DEC = (float*)alloc((size_t)147456 * 4);
  unsigned short* OATTb = (unsigned short*)alloc((size_t)786432 * 2);
  char* U = alloc((size_t)14155776);  // union region, 13.5 MiB
  // phase A (dead after decision): A0f/A1f
  float* A0f = (float*)U;                          // 6 MiB
  float* A1f = (float*)(U + (size_t)6291456);      // 6 MiB
  // phase B (after attention): F2, O1f, O1b, Hfb
  float* F2 = (float*)U;                           // 3 MiB
  float* O1f = (float*)(U + (size_t)3145728);      // 3 MiB
  unsigned short* O1b = (unsigned short*)(U + (size_t)6291456);   // 1.5 MiB
  unsigned short* Hfb = (unsigned short*)(U + (size_t)7864320);   // 6 MiB

  dim3 blk(256);

  // ---- weight transpose+cast ----
  WtJobs jobs;
  int ts = 0;
  auto setjob = [&](int idx, const float* s, unsigned short* d, int K, int N) {
    jobs.j[idx].src = s; jobs.j[idx].dst = d;
    jobs.j[idx].K = K; jobs.j[idx].N = N; jobs.j[idx].tstart = ts;
    ts += (K / 32) * (N / 32);
  };
  setjob(0, w_qs, WQS, 1024, 1024);
  setjob(1, w_ks, WKS, 1024, 1024);
  setjob(2, w_vs, WVS, 1024, 1024);
  setjob(3, w_ds0, WD0, 1024, 1024);
  setjob(4, w_ds1, WD1, 1024, 1024);
  setjob(5, dc_w1, WW1, 2048, 2048);
  setjob(6, w_fc, WFC, 1024, 1024);
  setjob(7, ffn_w1, WF1, 1024, 4096);
  setjob(8, ffn_w2, WF2, 4096, 1024);
  wt_transpose<<<dim3(ts), blk, 0, stream>>>(jobs);

  concat3<<<dim3(768), blk, 0, stream>>>((const float4*)in_t,
                                         (const float4*)in_a,
                                         (const float4*)in_v,
                                         (float4*)Xf, (u16x4*)Xb);

  // ---- 5 projections in one launch (N=1024, K=1024, bf16 out) ----
  GemmBatch proj{};
  unsigned short* pouts[5] = {Qb, Kb, Vb, D0b, D1b};
  const unsigned short* pws[5] = {WQS, WKS, WVS, WD0, WD1};
  for (int z = 0; z < 5; ++z) {
    proj.op[z].A = Xb; proj.op[z].B = pws[z];
    proj.op[z].bias = nullptr; proj.op[z].add = nullptr;
    proj.op[z].Cf = nullptr; proj.op[z].Cb = pouts[z];
    proj.op[z].lda = 1024; proj.op[z].ldb = 1024;
    proj.op[z].N = 1024; proj.op[z].K = 1024; proj.op[z].relu = 0;
  }
  gemm_mfma<<<dim3(16, 12, 5), blk, 0, stream>>>(proj);

  // ---- A0 = D0 @ dc_w1[D:], A1 = D1 @ dc_w1[:D] + dc_b1  (N=2048) ----
  GemmBatch pair{};
  pair.op[0].A = D0b; pair.op[0].B = WW1 + 1024;  // k-offset 1024 in Wt
  pair.op[0].bias = nullptr; pair.op[0].add = nullptr;
  pair.op[0].Cf = A0f; pair.op[0].Cb = nullptr;
  pair.op[0].lda = 1024; pair.op[0].ldb = 2048;
  pair.op[0].N = 2048; pair.op[0].K = 1024; pair.op[0].relu = 0;
  pair.op[1] = pair.op[0];
  pair.op[1].A = D1b; pair.op[1].B = WW1; pair.op[1].bias = dc_b1;
  pair.op[1].Cf = A1f;
  gemm_mfma<<<dim3(32, 12, 2), blk, 0, stream>>>(pair);

  decision_kernel<<<dim3(16, 4, 9), blk, 0, stream>>>(A1f, A0f, dc_w2, dc_b2,
                                                      DEC);

  attn_kernel<<<dim3(16, 4, 3), blk, 0, stream>>>(Qb, Kb, Vb, DEC, mask, OATTb);

  // ---- fc: F2 = OATT @ w_fc + X ----
  GemmBatch fc{};
  fc.op[0].A = OATTb; fc.op[0].B = WFC;
  fc.op[0].bias = nullptr; fc.op[0].add = Xf;
  fc.op[0].Cf = F2; fc.op[0].Cb = nullptr;
  fc.op[0].lda = 1024; fc.op[0].ldb = 1024;
  fc.op[0].N = 1024; fc.op[0].K = 1024; fc.op[0].relu = 0;
  gemm_mfma<<<dim3(16, 12, 1), blk, 0, stream>>>(fc);

  ln_kernel<<<dim3(768), blk, 0, stream>>>(F2, ln1_g, ln1_b, O1f, O1b);

  // ---- FFN1: Hf = relu(O1 @ w1 + b1)  (N=4096, bf16 out) ----
  GemmBatch f1{};
  f1.op[0].A = O1b; f1.op[0].B = WF1;
  f1.op[0].bias = ffn_b1; f1.op[0].add = nullptr;
  f1.op[0].Cf = nullptr; f1.op[0].Cb = Hfb;
  f1.op[0].lda = 1024; f1.op[0].ldb = 1024;
  f1.op[0].N = 4096; f1.op[0].K = 1024; f1.op[0].relu = 1;
  gemm_mfma<<<dim3(64, 12, 1), blk, 0, stream>>>(f1);

  // ---- FFN2: F2 = Hf @ w2 + b2 + O1 ----
  GemmBatch f2{};
  f2.op[0].A = Hfb; f2.op[0].B = WF2;
  f2.op[0].bias = ffn_b2; f2.op[0].add = O1f;
  f2.op[0].Cf = F2; f2.op[0].Cb = nullptr;
  f2.op[0].lda = 4096; f2.op[0].ldb = 4096;
  f2.op[0].N = 1024; f2.op[0].K = 4096; f2.op[0].relu = 0;
  gemm_mfma<<<dim3(16, 12, 1), blk, 0, stream>>>(f2);

  ln_kernel<<<dim3(768), blk, 0, stream>>>(F2, ln2_g, ln2_b, out, nullptr);
}

// Round 4
// 216.592 us; speedup vs baseline: 4.4087x; 1.4052x over previous
//
#include <hip/hip_runtime.h>
#include <math.h>

// ---------------------------------------------------------------------------
// MMModel bf16-MFMA implementation. B=4, L=64, DM=1024, H=16, DK=DV=64,
// D=1024, DI=4096, nm=3. Row convention: row = (i*B + b)*L + l  (768 rows).
// ---------------------------------------------------------------------------

#define NEGV (-1000000000.0f)

typedef float f32x4 __attribute__((ext_vector_type(4)));
typedef short short8 __attribute__((ext_vector_type(8)));
typedef unsigned short u16x8 __attribute__((ext_vector_type(8)));
typedef unsigned short u16x4 __attribute__((ext_vector_type(4)));

static __device__ __forceinline__ unsigned short f2bf(float f) {
  unsigned u = __builtin_bit_cast(unsigned, f);
  u += 0x7fffu + ((u >> 16) & 1u);
  return (unsigned short)(u >> 16);
}
static __device__ __forceinline__ float bf2f(unsigned short h) {
  return __builtin_bit_cast(float, ((unsigned)h) << 16);
}

// ---------------- concat inputs into Xf[768][1024] f32 + Xb bf16 ------------
__global__ __launch_bounds__(256) void concat3(const float4* __restrict__ t,
                                               const float4* __restrict__ a,
                                               const float4* __restrict__ v,
                                               float4* __restrict__ Xf,
                                               u16x4* __restrict__ Xb) {
  int id = blockIdx.x * 256 + threadIdx.x;  // 768*256 float4s
  int m = id >> 16;
  int off = id & 65535;
  const float4* s = (m == 0) ? t : (m == 1) ? a : v;
  float4 val = s[off];
  Xf[id] = val;
  u16x4 bb;
  bb.x = f2bf(val.x); bb.y = f2bf(val.y);
  bb.z = f2bf(val.z); bb.w = f2bf(val.w);
  Xb[id] = bb;
}

// ---------------- weight transpose + f32->bf16: dst[n][k] = src[k][n] -------
struct WtJob { const float* src; unsigned short* dst; int K, N, tstart; };
struct WtJobs { WtJob j[9]; };

__global__ __launch_bounds__(256) void wt_transpose(WtJobs jobs) {
  __shared__ float Ls[32][33];
  int ji = 0;
#pragma unroll
  for (int t = 1; t < 9; ++t)
    if ((int)blockIdx.x >= jobs.j[t].tstart) ji = t;
  const WtJob jb = jobs.j[ji];
  int local = blockIdx.x - jb.tstart;
  int ntx = jb.N >> 5;
  int tk = local / ntx, tn = local - tk * ntx;
  const int tid = threadIdx.x;
  const int r = tid >> 3, c = (tid & 7) * 4;
  float4 v = *(const float4*)(jb.src + (size_t)(tk * 32 + r) * jb.N + tn * 32 + c);
  Ls[r][c + 0] = v.x; Ls[r][c + 1] = v.y;
  Ls[r][c + 2] = v.z; Ls[r][c + 3] = v.w;
  __syncthreads();
  u16x4 o;
  o.x = f2bf(Ls[c + 0][r]);
  o.y = f2bf(Ls[c + 1][r]);
  o.z = f2bf(Ls[c + 2][r]);
  o.w = f2bf(Ls[c + 3][r]);
  *(u16x4*)(jb.dst + (size_t)(tn * 32 + r) * jb.K + tk * 32 + c) = o;
}

// ---------------- bf16 MFMA GEMM -------------------------------------------
// C[M=768][N] = A[768][K](bf16) * Wt[N][K](bf16)^T  (+bias)(+add f32)(relu)
struct GemmOp {
  const unsigned short* A;
  const unsigned short* B;   // Wt, row n, col k, stride ldb
  const float* bias;         // [N] or null
  const float* add;          // [768][N] f32 or null
  float* Cf;                 // or null
  unsigned short* Cb;        // or null
  int lda, ldb, N, K, relu;
};
struct GemmBatch { GemmOp op[5]; };

__global__ __launch_bounds__(256, 2) void gemm_mfma(GemmBatch batch) {
  const GemmOp g = batch.op[blockIdx.z];
  __shared__ unsigned short As[64][72];
  __shared__ unsigned short Bs[64][72];
  const int bm = blockIdx.y * 64, bn = blockIdx.x * 64;
  const int tid = threadIdx.x;
  const int l = tid & 63, w = tid >> 6;
  const int wr = (w >> 1) * 32, wc = (w & 1) * 32;
  const int lr = l & 15, lg = l >> 4;
  const int sr = tid >> 2, sc = (tid & 3) * 16;
  f32x4 acc[2][2] = {};
  const unsigned short* ap = g.A + (size_t)(bm + sr) * g.lda + sc;
  const unsigned short* bp = g.B + (size_t)(bn + sr) * g.ldb + sc;
  for (int k0 = 0; k0 < g.K; k0 += 64) {
    __syncthreads();
    u16x8 av0 = *(const u16x8*)(ap + k0);
    u16x8 av1 = *(const u16x8*)(ap + k0 + 8);
    u16x8 bv0 = *(const u16x8*)(bp + k0);
    u16x8 bv1 = *(const u16x8*)(bp + k0 + 8);
    *(u16x8*)&As[sr][sc] = av0;
    *(u16x8*)&As[sr][sc + 8] = av1;
    *(u16x8*)&Bs[sr][sc] = bv0;
    *(u16x8*)&Bs[sr][sc + 8] = bv1;
    __syncthreads();
#pragma unroll
    for (int kk = 0; kk < 64; kk += 32) {
      short8 af0 = *(const short8*)&As[wr + 0 + lr][kk + lg * 8];
      short8 af1 = *(const short8*)&As[wr + 16 + lr][kk + lg * 8];
      short8 bf0 = *(const short8*)&Bs[wc + 0 + lr][kk + lg * 8];
      short8 bf1 = *(const short8*)&Bs[wc + 16 + lr][kk + lg * 8];
      acc[0][0] = __builtin_amdgcn_mfma_f32_16x16x32_bf16(af0, bf0, acc[0][0], 0, 0, 0);
      acc[0][1] = __builtin_amdgcn_mfma_f32_16x16x32_bf16(af0, bf1, acc[0][1], 0, 0, 0);
      acc[1][0] = __builtin_amdgcn_mfma_f32_16x16x32_bf16(af1, bf0, acc[1][0], 0, 0, 0);
      acc[1][1] = __builtin_amdgcn_mfma_f32_16x16x32_bf16(af1, bf1, acc[1][1], 0, 0, 0);
    }
  }
#pragma unroll
  for (int n = 0; n < 2; ++n) {
    const int col = bn + wc + n * 16 + lr;
    const float bv = g.bias ? g.bias[col] : 0.0f;
#pragma unroll
    for (int m = 0; m < 2; ++m) {
#pragma unroll
      for (int ii = 0; ii < 4; ++ii) {
        const int row = bm + wr + m * 16 + lg * 4 + ii;
        float v = acc[m][n][ii] + bv;
        if (g.add) v += g.add[(size_t)row * g.N + col];
        if (g.relu) v = fmaxf(v, 0.0f);
        if (g.Cf) g.Cf[(size_t)row * g.N + col] = v;
        if (g.Cb) g.Cb[(size_t)row * g.N + col] = f2bf(v);
      }
    }
  }
}

// ---------------- decision gate (UNCHANGED numerics) ------------------------
__global__ __launch_bounds__(256) void decision_kernel(
    const float* __restrict__ A1, const float* __restrict__ A0,
    const float* __restrict__ w2, const float* __restrict__ b2,
    float* __restrict__ DEC) {
  __shared__ float sA1[16][132];
  __shared__ float sA0[16][132];
  __shared__ float sW2[128][2];
  const int b = blockIdx.y;
  const int p = blockIdx.z;
  const int i = p / 3, j = p % 3;
  const int qt = (blockIdx.x >> 2) * 16, kt = (blockIdx.x & 3) * 16;
  const int tid = threadIdx.x;
  const int tq = tid >> 4, tk = tid & 15;
  const float* a1base = A1 + ((size_t)(j * 4 + b) * 64 + qt) * 2048;
  const float* a0base = A0 + ((size_t)(i * 4 + b) * 64 + kt) * 2048;
  const int sr = tid >> 4, sc2 = (tid & 15) * 8;
  float acc0 = 0.f, acc1 = 0.f;
  for (int d0 = 0; d0 < 2048; d0 += 128) {
    __syncthreads();
    *(float4*)&sA1[sr][sc2] = *(const float4*)(a1base + (size_t)sr * 2048 + d0 + sc2);
    *(float4*)&sA1[sr][sc2 + 4] = *(const float4*)(a1base + (size_t)sr * 2048 + d0 + sc2 + 4);
    *(float4*)&sA0[sr][sc2] = *(const float4*)(a0base + (size_t)sr * 2048 + d0 + sc2);
    *(float4*)&sA0[sr][sc2 + 4] = *(const float4*)(a0base + (size_t)sr * 2048 + d0 + sc2 + 4);
    if (tid < 128) {
      float2 wv = *(const float2*)(w2 + (size_t)(d0 + tid) * 2);
      sW2[tid][0] = wv.x; sW2[tid][1] = wv.y;
    }
    __syncthreads();
#pragma unroll 8
    for (int dd = 0; dd < 128; ++dd) {
      float v = fmaxf(sA1[tq][dd] + sA0[tk][dd], 0.f);
      acc0 = fmaf(v, sW2[dd][0], acc0);
      acc1 = fmaf(v, sW2[dd][1], acc1);
    }
  }
  float l0 = acc0 + b2[0], l1 = acc1 + b2[1];
  DEC[((size_t)p * 4 + b) * 4096 + (qt + tq) * 64 + kt + tk] =
      (l1 > l0) ? NEGV : 0.f;
}

// ---------------- MFMA attention (race-fixed: full barrier discipline) ------
// grid (H=16, B=4, nm=3), block 256 (4 waves x 16 queries).
// Swapped QK^T: S^T[key][q] = mfma(Kfrag, Qfrag). Softmax in-register.
// P hi/lo bf16 two-pass PV; every LDS write->read phase is barrier-separated.
__global__ __launch_bounds__(256) void attn_mfma(
    const unsigned short* __restrict__ Qa, const unsigned short* __restrict__ Ka,
    const unsigned short* __restrict__ Va, const float* __restrict__ DEC,
    const int* __restrict__ mask, unsigned short* __restrict__ O) {
  __shared__ __align__(16) char sm[49408];
  char* KsP = sm;          // [192][64] bf16 K tiles; reused as P[4][16][192] bf16
  char* Vt = sm + 24576;   // [64][192] bf16 V^T
  float* invs = (float*)(sm + 49152);  // [64]

  const int h = blockIdx.x, b = blockIdx.y, i = blockIdx.z;
  const int tid = threadIdx.x;
  const int l = tid & 63, w = tid >> 6;
  const int l15 = l & 15, lg = l >> 4;

  // ---- stage K rows (swizzled) and V transposed (swizzled) ----
#pragma unroll
  for (int rep = 0; rep < 6; ++rep) {
    int flat = rep * 256 + tid;       // 0..1535
    int key = flat >> 3, c8 = flat & 7;
    int j = key >> 6, kl = key & 63;
    const size_t rowoff = (((size_t)(j * 4 + b) * 64 + kl) * 1024) + h * 64 + c8 * 8;
    u16x8 kv = *(const u16x8*)(Ka + rowoff);
    *(u16x8*)(KsP + ((key * 128 + c8 * 16) ^ ((key & 7) << 4))) = kv;
    u16x8 vv = *(const u16x8*)(Va + rowoff);
#pragma unroll
    for (int jj = 0; jj < 8; ++jj) {
      int d = c8 * 8 + jj;
      *(unsigned short*)(Vt + ((d * 384 + key * 2) ^ ((d & 7) << 4))) = vv[jj];
    }
  }

  // ---- Q fragments straight to registers (each wave: its 16 queries) ----
  const int qg = w * 16 + l15;  // this lane's query (as S^T column)
  const unsigned short* qsrc =
      Qa + (((size_t)(i * 4 + b) * 64 + qg) * 1024) + h * 64 + lg * 8;
  short8 qf0 = *(const short8*)(qsrc);
  short8 qf1 = *(const short8*)(qsrc + 32);

  __syncthreads();  // (1) staging visible

  // ---- S^T = K · Q^T : 12 key-tiles x (K=64 as 2x32) ----
  f32x4 s[12];
#pragma unroll
  for (int t = 0; t < 12; ++t) {
    const int key = t * 16 + l15;
    const int swz = (key & 7) << 4;
    short8 kf0 = *(const short8*)(KsP + ((key * 128 + 0 + lg * 16) ^ swz));
    short8 kf1 = *(const short8*)(KsP + ((key * 128 + 64 + lg * 16) ^ swz));
    f32x4 z = {0.f, 0.f, 0.f, 0.f};
    z = __builtin_amdgcn_mfma_f32_16x16x32_bf16(kf0, qf0, z, 0, 0, 0);
    z = __builtin_amdgcn_mfma_f32_16x16x32_bf16(kf1, qf1, z, 0, 0, 0);
    s[t] = z;
  }

  // ---- mask / dec / scale, then softmax over 192 keys (rows of S^T) ----
  int mk[4][4];
#pragma unroll
  for (int t4 = 0; t4 < 4; ++t4)
#pragma unroll
    for (int r = 0; r < 4; ++r)
      mk[t4][r] = mask[((size_t)b * 64 + qg) * 64 + t4 * 16 + lg * 4 + r];

  float mx = -3.0e38f;
#pragma unroll
  for (int t = 0; t < 12; ++t) {
    const float* dbase =
        DEC + (((size_t)(i * 3 + (t >> 2)) * 4 + b) * 4096) + qg * 64;
#pragma unroll
    for (int r = 0; r < 4; ++r) {
      const int kl = (t & 3) * 16 + lg * 4 + r;  // key % 64
      float sv = s[t][r] * 0.125f + dbase[kl];
      if (mk[t & 3][r] == 0) sv = NEGV;
      s[t][r] = sv;
      mx = fmaxf(mx, sv);
    }
  }
  mx = fmaxf(mx, __shfl_xor(mx, 16));
  mx = fmaxf(mx, __shfl_xor(mx, 32));
  float sum = 0.f;
#pragma unroll
  for (int t = 0; t < 12; ++t)
#pragma unroll
    for (int r = 0; r < 4; ++r) {
      float p = __expf(s[t][r] - mx);
      s[t][r] = p;
      sum += p;
    }
  sum += __shfl_xor(sum, 16);
  sum += __shfl_xor(sum, 32);
  if (l < 16) invs[w * 16 + l] = 1.0f / sum;

  __syncthreads();  // (2) all K-tile reads done; KsP becomes P storage

  char* Pmy = KsP + w * 6144;  // this wave's P[16][192] bf16
  const int pswz = (l15 & 7) << 4;

  // ---- write P_hi ----
#pragma unroll
  for (int t = 0; t < 12; ++t)
#pragma unroll
    for (int r = 0; r < 4; ++r) {
      const int key = t * 16 + lg * 4 + r;
      *(unsigned short*)(Pmy + ((l15 * 384 + key * 2) ^ pswz)) = f2bf(s[t][r]);
    }
  __syncthreads();  // (3) P_hi visible before any read

  f32x4 o[4] = {};
#pragma unroll
  for (int kc = 0; kc < 6; ++kc) {
    short8 pf = *(const short8*)(Pmy + ((l15 * 384 + kc * 64 + lg * 16) ^ pswz));
#pragma unroll
    for (int dt = 0; dt < 4; ++dt) {
      const int d = dt * 16 + l15;
      short8 vf = *(const short8*)(Vt + ((d * 384 + kc * 64 + lg * 16) ^ ((d & 7) << 4)));
      o[dt] = __builtin_amdgcn_mfma_f32_16x16x32_bf16(pf, vf, o[dt], 0, 0, 0);
    }
  }
  __syncthreads();  // (4) all P_hi reads done before overwrite

  // ---- write P_lo = P - bf16(P) ----
#pragma unroll
  for (int t = 0; t < 12; ++t)
#pragma unroll
    for (int r = 0; r < 4; ++r) {
      const int key = t * 16 + lg * 4 + r;
      float p = s[t][r];
      float lo = p - bf2f(f2bf(p));
      *(unsigned short*)(Pmy + ((l15 * 384 + key * 2) ^ pswz)) = f2bf(lo);
    }
  __syncthreads();  // (5) P_lo visible before any read

#pragma unroll
  for (int kc = 0; kc < 6; ++kc) {
    short8 pf = *(const short8*)(Pmy + ((l15 * 384 + kc * 64 + lg * 16) ^ pswz));
#pragma unroll
    for (int dt = 0; dt < 4; ++dt) {
      const int d = dt * 16 + l15;
      short8 vf = *(const short8*)(Vt + ((d * 384 + kc * 64 + lg * 16) ^ ((d & 7) << 4)));
      o[dt] = __builtin_amdgcn_mfma_f32_16x16x32_bf16(pf, vf, o[dt], 0, 0, 0);
    }
  }

  // ---- epilogue: O[q][d] * inv(q) -> bf16 ----
#pragma unroll
  for (int dt = 0; dt < 4; ++dt)
#pragma unroll
    for (int r = 0; r < 4; ++r) {
      const int ql = lg * 4 + r;
      const float inv = invs[w * 16 + ql];
      const int d = dt * 16 + l15;
      O[(((size_t)(i * 4 + b) * 64 + w * 16 + ql) * 1024) + h * 64 + d] =
          f2bf(o[dt][r] * inv);
    }
}

// ---------------- layer norm over rows of 1024 ------------------------------
__global__ __launch_bounds__(256) void ln_kernel(const float* __restrict__ X,
                                                 const float* __restrict__ g,
                                                 const float* __restrict__ be,
                                                 float* __restrict__ Y,
                                                 unsigned short* __restrict__ Yb) {
  __shared__ float rs[8];
  int row = blockIdx.x, tid = threadIdx.x;
  const float* x = X + (size_t)row * 1024 + tid * 4;
  float4 v = *(const float4*)x;
  float s = v.x + v.y + v.z + v.w;
  float s2 = v.x * v.x + v.y * v.y + v.z * v.z + v.w * v.w;
#pragma unroll
  for (int off = 32; off > 0; off >>= 1) {
    s += __shfl_down(s, off);
    s2 += __shfl_down(s2, off);
  }
  int lane = tid & 63, wid = tid >> 6;
  if (lane == 0) { rs[wid * 2] = s; rs[wid * 2 + 1] = s2; }
  __syncthreads();
  if (tid == 0) {
    float aa = rs[0] + rs[2] + rs[4] + rs[6];
    float cc = rs[1] + rs[3] + rs[5] + rs[7];
    rs[0] = aa; rs[1] = cc;
  }
  __syncthreads();
  float mu = rs[0] * (1.0f / 1024.0f);
  float var = rs[1] * (1.0f / 1024.0f) - mu * mu;
  var = fmaxf(var, 0.f);
  float inv = 1.0f / sqrtf(var + 1e-6f);
  float4 gv = *(const float4*)(g + tid * 4);
  float4 bv = *(const float4*)(be + tid * 4);
  float4 o;
  o.x = (v.x - mu) * inv * gv.x + bv.x;
  o.y = (v.y - mu) * inv * gv.y + bv.y;
  o.z = (v.z - mu) * inv * gv.z + bv.z;
  o.w = (v.w - mu) * inv * gv.w + bv.w;
  *(float4*)(Y + (size_t)row * 1024 + tid * 4) = o;
  if (Yb) {
    u16x4 ob;
    ob.x = f2bf(o.x); ob.y = f2bf(o.y); ob.z = f2bf(o.z); ob.w = f2bf(o.w);
    *(u16x4*)(Yb + (size_t)row * 1024 + tid * 4) = ob;
  }
}

// ---------------------------------------------------------------------------
extern "C" void kernel_launch(void* const* d_in, const int* in_sizes, int n_in,
                              void* d_out, int out_size, void* d_ws,
                              size_t ws_size, hipStream_t stream) {
  const float* in_t = (const float*)d_in[0];
  const float* in_a = (const float*)d_in[1];
  const float* in_v = (const float*)d_in[2];
  const int* mask = (const int*)d_in[3];
  const float* w_qs = (const float*)d_in[4];
  const float* w_ks = (const float*)d_in[5];
  const float* w_vs = (const float*)d_in[6];
  const float* w_ds0 = (const float*)d_in[7];
  const float* w_ds1 = (const float*)d_in[8];
  const float* dc_w1 = (const float*)d_in[9];
  const float* dc_b1 = (const float*)d_in[10];
  const float* dc_w2 = (const float*)d_in[11];
  const float* dc_b2 = (const float*)d_in[12];
  const float* w_fc = (const float*)d_in[13];
  const float* ln1_g = (const float*)d_in[14];
  const float* ln1_b = (const float*)d_in[15];
  const float* ffn_w1 = (const float*)d_in[16];
  const float* ffn_b1 = (const float*)d_in[17];
  const float* ffn_w2 = (const float*)d_in[18];
  const float* ffn_b2 = (const float*)d_in[19];
  const float* ln2_g = (const float*)d_in[20];
  const float* ln2_b = (const float*)d_in[21];
  float* out = (float*)d_out;

  char* p = (char*)d_ws;
  auto alloc = [&](size_t bytes) {
    char* r = p;
    p += (bytes + 255) & ~(size_t)255;
    return r;
  };
  unsigned short* WQS = (unsigned short*)alloc(1024 * 1024 * 2);
  unsigned short* WKS = (unsigned short*)alloc(1024 * 1024 * 2);
  unsigned short* WVS = (unsigned short*)alloc(1024 * 1024 * 2);
  unsigned short* WD0 = (unsigned short*)alloc(1024 * 1024 * 2);
  unsigned short* WD1 = (unsigned short*)alloc(1024 * 1024 * 2);
  unsigned short* WW1 = (unsigned short*)alloc((size_t)2048 * 2048 * 2);
  unsigned short* WFC = (unsigned short*)alloc(1024 * 1024 * 2);
  unsigned short* WF1 = (unsigned short*)alloc((size_t)4096 * 1024 * 2);
  unsigned short* WF2 = (unsigned short*)alloc((size_t)1024 * 4096 * 2);
  float* Xf = (float*)alloc((size_t)786432 * 4);
  unsigned short* Xb = (unsigned short*)alloc((size_t)786432 * 2);
  unsigned short* Qb = (unsigned short*)alloc((size_t)786432 * 2);
  unsigned short* Kb = (unsigned short*)alloc((size_t)786432 * 2);
  unsigned short* Vb = (unsigned short*)alloc((size_t)786432 * 2);
  unsigned short* D0b = (unsigned short*)alloc((size_t)786432 * 2);
  unsigned short* D1b = (unsigned short*)alloc((size_t)786432 * 2);
  float* DEC = (float*)alloc((size_t)147456 * 4);
  unsigned short* OATTb = (unsigned short*)alloc((size_t)786432 * 2);
  char* U = alloc((size_t)14155776);
  float* A0f = (float*)U;
  float* A1f = (float*)(U + (size_t)6291456);
  float* F2 = (float*)U;
  float* O1f = (float*)(U + (size_t)3145728);
  unsigned short* O1b = (unsigned short*)(U + (size_t)6291456);
  unsigned short* Hfb = (unsigned short*)(U + (size_t)7864320);

  dim3 blk(256);

  WtJobs jobs;
  int ts = 0;
  auto setjob = [&](int idx, const float* s, unsigned short* d, int K, int N) {
    jobs.j[idx].src = s; jobs.j[idx].dst = d;
    jobs.j[idx].K = K; jobs.j[idx].N = N; jobs.j[idx].tstart = ts;
    ts += (K / 32) * (N / 32);
  };
  setjob(0, w_qs, WQS, 1024, 1024);
  setjob(1, w_ks, WKS, 1024, 1024);
  setjob(2, w_vs, WVS, 1024, 1024);
  setjob(3, w_ds0, WD0, 1024, 1024);
  setjob(4, w_ds1, WD1, 1024, 1024);
  setjob(5, dc_w1, WW1, 2048, 2048);
  setjob(6, w_fc, WFC, 1024, 1024);
  setjob(7, ffn_w1, WF1, 1024, 4096);
  setjob(8, ffn_w2, WF2, 4096, 1024);
  wt_transpose<<<dim3(ts), blk, 0, stream>>>(jobs);

  concat3<<<dim3(768), blk, 0, stream>>>((const float4*)in_t,
                                         (const float4*)in_a,
                                         (const float4*)in_v,
                                         (float4*)Xf, (u16x4*)Xb);

  GemmBatch proj{};
  unsigned short* pouts[5] = {Qb, Kb, Vb, D0b, D1b};
  const unsigned short* pws[5] = {WQS, WKS, WVS, WD0, WD1};
  for (int z = 0; z < 5; ++z) {
    proj.op[z].A = Xb; proj.op[z].B = pws[z];
    proj.op[z].bias = nullptr; proj.op[z].add = nullptr;
    proj.op[z].Cf = nullptr; proj.op[z].Cb = pouts[z];
    proj.op[z].lda = 1024; proj.op[z].ldb = 1024;
    proj.op[z].N = 1024; proj.op[z].K = 1024; proj.op[z].relu = 0;
  }
  gemm_mfma<<<dim3(16, 12, 5), blk, 0, stream>>>(proj);

  GemmBatch pair{};
  pair.op[0].A = D0b; pair.op[0].B = WW1 + 1024;
  pair.op[0].bias = nullptr; pair.op[0].add = nullptr;
  pair.op[0].Cf = A0f; pair.op[0].Cb = nullptr;
  pair.op[0].lda = 1024; pair.op[0].ldb = 2048;
  pair.op[0].N = 2048; pair.op[0].K = 1024; pair.op[0].relu = 0;
  pair.op[1] = pair.op[0];
  pair.op[1].A = D1b; pair.op[1].B = WW1; pair.op[1].bias = dc_b1;
  pair.op[1].Cf = A1f;
  gemm_mfma<<<dim3(32, 12, 2), blk, 0, stream>>>(pair);

  decision_kernel<<<dim3(16, 4, 9), blk, 0, stream>>>(A1f, A0f, dc_w2, dc_b2,
                                                      DEC);

  attn_mfma<<<dim3(16, 4, 3), blk, 0, stream>>>(Qb, Kb, Vb, DEC, mask, OATTb);

  GemmBatch fc{};
  fc.op[0].A = OATTb; fc.op[0].B = WFC;
  fc.op[0].bias = nullptr; fc.op[0].add = Xf;
  fc.op[0].Cf = F2; fc.op[0].Cb = nullptr;
  fc.op[0].lda = 1024; fc.op[0].ldb = 1024;
  fc.op[0].N = 1024; fc.op[0].K = 1024; fc.op[0].relu = 0;
  gemm_mfma<<<dim3(16, 12, 1), blk, 0, stream>>>(fc);

  ln_kernel<<<dim3(768), blk, 0, stream>>>(F2, ln1_g, ln1_b, O1f, O1b);

  GemmBatch f1{};
  f1.op[0].A = O1b; f1.op[0].B = WF1;
  f1.op[0].bias = ffn_b1; f1.op[0].add = nullptr;
  f1.op[0].Cf = nullptr; f1.op[0].Cb = Hfb;
  f1.op[0].lda = 1024; f1.op[0].ldb = 1024;
  f1.op[0].N = 4096; f1.op[0].K = 1024; f1.op[0].relu = 1;
  gemm_mfma<<<dim3(64, 12, 1), blk, 0, stream>>>(f1);

  GemmBatch f2{};
  f2.op[0].A = Hfb; f2.op[0].B = WF2;
  f2.op[0].bias = ffn_b2; f2.op[0].add = O1f;
  f2.op[0].Cf = F2; f2.op[0].Cb = nullptr;
  f2.op[0].lda = 4096; f2.op[0].ldb = 4096;
  f2.op[0].N = 1024; f2.op[0].K = 4096; f2.op[0].relu = 0;
  gemm_mfma<<<dim3(16, 12, 1), blk, 0, stream>>>(f2);

  ln_kernel<<<dim3(768), blk, 0, stream>>>(F2, ln2_g, ln2_b, out, nullptr);
}

// Round 5
// 198.502 us; speedup vs baseline: 4.8105x; 1.0911x over previous
//
#include <hip/hip_runtime.h>
#include <math.h>

// ---------------------------------------------------------------------------
// MMModel bf16-MFMA implementation. B=4, L=64, DM=1024, H=16, DK=DV=64,
// D=1024, DI=4096, nm=3. Row convention: row = (i*B + b)*L + l  (768 rows).
// ---------------------------------------------------------------------------

#define NEGV (-1000000000.0f)

typedef float f32x4 __attribute__((ext_vector_type(4)));
typedef short short8 __attribute__((ext_vector_type(8)));
typedef unsigned short u16x8 __attribute__((ext_vector_type(8)));
typedef unsigned short u16x4 __attribute__((ext_vector_type(4)));

static __device__ __forceinline__ unsigned short f2bf(float f) {
  unsigned u = __builtin_bit_cast(unsigned, f);
  u += 0x7fffu + ((u >> 16) & 1u);
  return (unsigned short)(u >> 16);
}
static __device__ __forceinline__ float bf2f(unsigned short h) {
  return __builtin_bit_cast(float, ((unsigned)h) << 16);
}

// ---------------- concat inputs into Xf[768][1024] f32 + Xb bf16 ------------
__global__ __launch_bounds__(256) void concat3(const float4* __restrict__ t,
                                               const float4* __restrict__ a,
                                               const float4* __restrict__ v,
                                               float4* __restrict__ Xf,
                                               u16x4* __restrict__ Xb) {
  int id = blockIdx.x * 256 + threadIdx.x;  // 768*256 float4s
  int m = id >> 16;
  int off = id & 65535;
  const float4* s = (m == 0) ? t : (m == 1) ? a : v;
  float4 val = s[off];
  Xf[id] = val;
  u16x4 bb;
  bb.x = f2bf(val.x); bb.y = f2bf(val.y);
  bb.z = f2bf(val.z); bb.w = f2bf(val.w);
  Xb[id] = bb;
}

// ---------------- weight transpose + f32->bf16: dst[n][k] = src[k][n] -------
struct WtJob { const float* src; unsigned short* dst; int K, N, tstart; };
struct WtJobs { WtJob j[9]; };

__global__ __launch_bounds__(256) void wt_transpose(WtJobs jobs) {
  __shared__ float Ls[32][33];
  int ji = 0;
#pragma unroll
  for (int t = 1; t < 9; ++t)
    if ((int)blockIdx.x >= jobs.j[t].tstart) ji = t;
  const WtJob jb = jobs.j[ji];
  int local = blockIdx.x - jb.tstart;
  int ntx = jb.N >> 5;
  int tk = local / ntx, tn = local - tk * ntx;
  const int tid = threadIdx.x;
  const int r = tid >> 3, c = (tid & 7) * 4;
  float4 v = *(const float4*)(jb.src + (size_t)(tk * 32 + r) * jb.N + tn * 32 + c);
  Ls[r][c + 0] = v.x; Ls[r][c + 1] = v.y;
  Ls[r][c + 2] = v.z; Ls[r][c + 3] = v.w;
  __syncthreads();
  u16x4 o;
  o.x = f2bf(Ls[c + 0][r]);
  o.y = f2bf(Ls[c + 1][r]);
  o.z = f2bf(Ls[c + 2][r]);
  o.w = f2bf(Ls[c + 3][r]);
  *(u16x4*)(jb.dst + (size_t)(tn * 32 + r) * jb.K + tk * 32 + c) = o;
}

// ---------------- bf16 MFMA GEMM -------------------------------------------
struct GemmOp {
  const unsigned short* A;
  const unsigned short* B;   // Wt, row n, col k, stride ldb
  const float* bias;         // [N] or null
  const float* add;          // [768][N] f32 or null
  float* Cf;                 // or null
  unsigned short* Cb;        // or null
  int lda, ldb, N, K, relu;
};
struct GemmBatch { GemmOp op[5]; };

__global__ __launch_bounds__(256, 2) void gemm_mfma(GemmBatch batch) {
  const GemmOp g = batch.op[blockIdx.z];
  __shared__ unsigned short As[64][72];
  __shared__ unsigned short Bs[64][72];
  const int bm = blockIdx.y * 64, bn = blockIdx.x * 64;
  const int tid = threadIdx.x;
  const int l = tid & 63, w = tid >> 6;
  const int wr = (w >> 1) * 32, wc = (w & 1) * 32;
  const int lr = l & 15, lg = l >> 4;
  const int sr = tid >> 2, sc = (tid & 3) * 16;
  f32x4 acc[2][2] = {};
  const unsigned short* ap = g.A + (size_t)(bm + sr) * g.lda + sc;
  const unsigned short* bp = g.B + (size_t)(bn + sr) * g.ldb + sc;
  for (int k0 = 0; k0 < g.K; k0 += 64) {
    __syncthreads();
    u16x8 av0 = *(const u16x8*)(ap + k0);
    u16x8 av1 = *(const u16x8*)(ap + k0 + 8);
    u16x8 bv0 = *(const u16x8*)(bp + k0);
    u16x8 bv1 = *(const u16x8*)(bp + k0 + 8);
    *(u16x8*)&As[sr][sc] = av0;
    *(u16x8*)&As[sr][sc + 8] = av1;
    *(u16x8*)&Bs[sr][sc] = bv0;
    *(u16x8*)&Bs[sr][sc + 8] = bv1;
    __syncthreads();
#pragma unroll
    for (int kk = 0; kk < 64; kk += 32) {
      short8 af0 = *(const short8*)&As[wr + 0 + lr][kk + lg * 8];
      short8 af1 = *(const short8*)&As[wr + 16 + lr][kk + lg * 8];
      short8 bf0 = *(const short8*)&Bs[wc + 0 + lr][kk + lg * 8];
      short8 bf1 = *(const short8*)&Bs[wc + 16 + lr][kk + lg * 8];
      acc[0][0] = __builtin_amdgcn_mfma_f32_16x16x32_bf16(af0, bf0, acc[0][0], 0, 0, 0);
      acc[0][1] = __builtin_amdgcn_mfma_f32_16x16x32_bf16(af0, bf1, acc[0][1], 0, 0, 0);
      acc[1][0] = __builtin_amdgcn_mfma_f32_16x16x32_bf16(af1, bf0, acc[1][0], 0, 0, 0);
      acc[1][1] = __builtin_amdgcn_mfma_f32_16x16x32_bf16(af1, bf1, acc[1][1], 0, 0, 0);
    }
  }
#pragma unroll
  for (int n = 0; n < 2; ++n) {
    const int col = bn + wc + n * 16 + lr;
    const float bv = g.bias ? g.bias[col] : 0.0f;
#pragma unroll
    for (int m = 0; m < 2; ++m) {
#pragma unroll
      for (int ii = 0; ii < 4; ++ii) {
        const int row = bm + wr + m * 16 + lg * 4 + ii;
        float v = acc[m][n][ii] + bv;
        if (g.add) v += g.add[(size_t)row * g.N + col];
        if (g.relu) v = fmaxf(v, 0.0f);
        if (g.Cf) g.Cf[(size_t)row * g.N + col] = v;
        if (g.Cb) g.Cb[(size_t)row * g.N + col] = f2bf(v);
      }
    }
  }
}

// ---------------- decision gate, pass 1: partial sums -----------------------
// grid (16 d-splits, B=4, 9 pairs), block 256. Each block: full 64x64 (q,k)
// outputs x 128 d. 4x4 outputs/thread, float2 LDS reads -> VALU-bound.
// PART[s][pp][b][q][k] = float2(acc0, acc1), fixed ascending-d chain per s.
__global__ __launch_bounds__(256) void decision_part(
    const float* __restrict__ A1, const float* __restrict__ A0,
    const float* __restrict__ w2, float2* __restrict__ PART) {
  __shared__ float2 sA1[64][34];  // [q][d-pair], stride 34 f2 (16B-aligned rows)
  __shared__ float2 sA0[64][34];  // [k][d-pair]
  __shared__ float2 sW2[64];      // (w0,w1) per d
  const int ds = blockIdx.x;      // 0..15 -> d range [ds*128, ds*128+128)
  const int b = blockIdx.y, pp = blockIdx.z;
  const int i = pp / 3, j = pp % 3;
  const int tid = threadIdx.x;
  const int tq = tid >> 4, tk = tid & 15;
  const float* a1base = A1 + ((size_t)(j * 4 + b) * 64) * 2048 + ds * 128;
  const float* a0base = A0 + ((size_t)(i * 4 + b) * 64) * 2048 + ds * 128;
  float acc[4][4][2] = {};
  for (int c = 0; c < 2; ++c) {   // two 64-d chunks
    __syncthreads();
    // stage 64 rows x 64 d of A1 and A0 (16 lanes per row, f32x4 each)
#pragma unroll
    for (int p16 = 0; p16 < 4; ++p16) {
      const int row = p16 * 16 + (tid >> 4);
      const int col = (tid & 15) * 4;
      float4 v1 = *(const float4*)(a1base + (size_t)row * 2048 + c * 64 + col);
      float4 v0 = *(const float4*)(a0base + (size_t)row * 2048 + c * 64 + col);
      float2* d1 = &sA1[row][(tid & 15) * 2];
      d1[0].x = v1.x; d1[0].y = v1.y; d1[1].x = v1.z; d1[1].y = v1.w;
      float2* d0 = &sA0[row][(tid & 15) * 2];
      d0[0].x = v0.x; d0[0].y = v0.y; d0[1].x = v0.z; d0[1].y = v0.w;
    }
    if (tid < 64)
      sW2[tid] = *(const float2*)(w2 + (size_t)(ds * 128 + c * 64 + tid) * 2);
    __syncthreads();
#pragma unroll 4
    for (int s = 0; s < 32; ++s) {   // d-pairs
      float2 a1v[4], a0v[4];
#pragma unroll
      for (int r = 0; r < 4; ++r) {
        a1v[r] = sA1[tq + 16 * r][s];
        a0v[r] = sA0[tk + 16 * r][s];
      }
      const float2 wA = sW2[2 * s], wB = sW2[2 * s + 1];
#pragma unroll
      for (int qr = 0; qr < 4; ++qr)
#pragma unroll
        for (int kr = 0; kr < 4; ++kr) {
          float v0 = fmaxf(a1v[qr].x + a0v[kr].x, 0.f);
          acc[qr][kr][0] = fmaf(v0, wA.x, acc[qr][kr][0]);
          acc[qr][kr][1] = fmaf(v0, wA.y, acc[qr][kr][1]);
          float v1 = fmaxf(a1v[qr].y + a0v[kr].y, 0.f);
          acc[qr][kr][0] = fmaf(v1, wB.x, acc[qr][kr][0]);
          acc[qr][kr][1] = fmaf(v1, wB.y, acc[qr][kr][1]);
        }
    }
  }
  float2* outp = PART + (size_t)ds * 147456 + ((size_t)pp * 4 + b) * 4096;
#pragma unroll
  for (int qr = 0; qr < 4; ++qr)
#pragma unroll
    for (int kr = 0; kr < 4; ++kr) {
      float2 o;
      o.x = acc[qr][kr][0];
      o.y = acc[qr][kr][1];
      outp[(tq + 16 * qr) * 64 + (tk + 16 * kr)] = o;
    }
}

// ---------------- decision gate, pass 2: reduce + compare -------------------
__global__ __launch_bounds__(256) void decision_reduce(
    const float2* __restrict__ PART, const float* __restrict__ b2,
    float* __restrict__ DEC) {
  const int out = blockIdx.x * 256 + threadIdx.x;  // 0..147455
  float acc0 = 0.f, acc1 = 0.f;
#pragma unroll
  for (int s = 0; s < 16; ++s) {
    float2 v = PART[(size_t)s * 147456 + out];
    acc0 += v.x;
    acc1 += v.y;
  }
  float l0 = acc0 + b2[0], l1 = acc1 + b2[1];
  DEC[out] = (l1 > l0) ? NEGV : 0.f;
}

// ---------------- MFMA attention (race-fixed: full barrier discipline) ------
__global__ __launch_bounds__(256) void attn_mfma(
    const unsigned short* __restrict__ Qa, const unsigned short* __restrict__ Ka,
    const unsigned short* __restrict__ Va, const float* __restrict__ DEC,
    const int* __restrict__ mask, unsigned short* __restrict__ O) {
  __shared__ __align__(16) char sm[49408];
  char* KsP = sm;          // [192][64] bf16 K tiles; reused as P[4][16][192] bf16
  char* Vt = sm + 24576;   // [64][192] bf16 V^T
  float* invs = (float*)(sm + 49152);  // [64]

  const int h = blockIdx.x, b = blockIdx.y, i = blockIdx.z;
  const int tid = threadIdx.x;
  const int l = tid & 63, w = tid >> 6;
  const int l15 = l & 15, lg = l >> 4;

#pragma unroll
  for (int rep = 0; rep < 6; ++rep) {
    int flat = rep * 256 + tid;       // 0..1535
    int key = flat >> 3, c8 = flat & 7;
    int j = key >> 6, kl = key & 63;
    const size_t rowoff = (((size_t)(j * 4 + b) * 64 + kl) * 1024) + h * 64 + c8 * 8;
    u16x8 kv = *(const u16x8*)(Ka + rowoff);
    *(u16x8*)(KsP + ((key * 128 + c8 * 16) ^ ((key & 7) << 4))) = kv;
    u16x8 vv = *(const u16x8*)(Va + rowoff);
#pragma unroll
    for (int jj = 0; jj < 8; ++jj) {
      int d = c8 * 8 + jj;
      *(unsigned short*)(Vt + ((d * 384 + key * 2) ^ ((d & 7) << 4))) = vv[jj];
    }
  }

  const int qg = w * 16 + l15;
  const unsigned short* qsrc =
      Qa + (((size_t)(i * 4 + b) * 64 + qg) * 1024) + h * 64 + lg * 8;
  short8 qf0 = *(const short8*)(qsrc);
  short8 qf1 = *(const short8*)(qsrc + 32);

  __syncthreads();  // (1) staging visible

  f32x4 s[12];
#pragma unroll
  for (int t = 0; t < 12; ++t) {
    const int key = t * 16 + l15;
    const int swz = (key & 7) << 4;
    short8 kf0 = *(const short8*)(KsP + ((key * 128 + 0 + lg * 16) ^ swz));
    short8 kf1 = *(const short8*)(KsP + ((key * 128 + 64 + lg * 16) ^ swz));
    f32x4 z = {0.f, 0.f, 0.f, 0.f};
    z = __builtin_amdgcn_mfma_f32_16x16x32_bf16(kf0, qf0, z, 0, 0, 0);
    z = __builtin_amdgcn_mfma_f32_16x16x32_bf16(kf1, qf1, z, 0, 0, 0);
    s[t] = z;
  }

  int mk[4][4];
#pragma unroll
  for (int t4 = 0; t4 < 4; ++t4)
#pragma unroll
    for (int r = 0; r < 4; ++r)
      mk[t4][r] = mask[((size_t)b * 64 + qg) * 64 + t4 * 16 + lg * 4 + r];

  float mx = -3.0e38f;
#pragma unroll
  for (int t = 0; t < 12; ++t) {
    const float* dbase =
        DEC + (((size_t)(i * 3 + (t >> 2)) * 4 + b) * 4096) + qg * 64;
#pragma unroll
    for (int r = 0; r < 4; ++r) {
      const int kl = (t & 3) * 16 + lg * 4 + r;
      float sv = s[t][r] * 0.125f + dbase[kl];
      if (mk[t & 3][r] == 0) sv = NEGV;
      s[t][r] = sv;
      mx = fmaxf(mx, sv);
    }
  }
  mx = fmaxf(mx, __shfl_xor(mx, 16));
  mx = fmaxf(mx, __shfl_xor(mx, 32));
  float sum = 0.f;
#pragma unroll
  for (int t = 0; t < 12; ++t)
#pragma unroll
    for (int r = 0; r < 4; ++r) {
      float p = __expf(s[t][r] - mx);
      s[t][r] = p;
      sum += p;
    }
  sum += __shfl_xor(sum, 16);
  sum += __shfl_xor(sum, 32);
  if (l < 16) invs[w * 16 + l] = 1.0f / sum;

  __syncthreads();  // (2) K-tile reads done; KsP becomes P storage

  char* Pmy = KsP + w * 6144;
  const int pswz = (l15 & 7) << 4;

#pragma unroll
  for (int t = 0; t < 12; ++t)
#pragma unroll
    for (int r = 0; r < 4; ++r) {
      const int key = t * 16 + lg * 4 + r;
      *(unsigned short*)(Pmy + ((l15 * 384 + key * 2) ^ pswz)) = f2bf(s[t][r]);
    }
  __syncthreads();  // (3) P_hi visible

  f32x4 o[4] = {};
#pragma unroll
  for (int kc = 0; kc < 6; ++kc) {
    short8 pf = *(const short8*)(Pmy + ((l15 * 384 + kc * 64 + lg * 16) ^ pswz));
#pragma unroll
    for (int dt = 0; dt < 4; ++dt) {
      const int d = dt * 16 + l15;
      short8 vf = *(const short8*)(Vt + ((d * 384 + kc * 64 + lg * 16) ^ ((d & 7) << 4)));
      o[dt] = __builtin_amdgcn_mfma_f32_16x16x32_bf16(pf, vf, o[dt], 0, 0, 0);
    }
  }
  __syncthreads();  // (4) P_hi reads done

#pragma unroll
  for (int t = 0; t < 12; ++t)
#pragma unroll
    for (int r = 0; r < 4; ++r) {
      const int key = t * 16 + lg * 4 + r;
      float p = s[t][r];
      float lo = p - bf2f(f2bf(p));
      *(unsigned short*)(Pmy + ((l15 * 384 + key * 2) ^ pswz)) = f2bf(lo);
    }
  __syncthreads();  // (5) P_lo visible

#pragma unroll
  for (int kc = 0; kc < 6; ++kc) {
    short8 pf = *(const short8*)(Pmy + ((l15 * 384 + kc * 64 + lg * 16) ^ pswz));
#pragma unroll
    for (int dt = 0; dt < 4; ++dt) {
      const int d = dt * 16 + l15;
      short8 vf = *(const short8*)(Vt + ((d * 384 + kc * 64 + lg * 16) ^ ((d & 7) << 4)));
      o[dt] = __builtin_amdgcn_mfma_f32_16x16x32_bf16(pf, vf, o[dt], 0, 0, 0);
    }
  }

#pragma unroll
  for (int dt = 0; dt < 4; ++dt)
#pragma unroll
    for (int r = 0; r < 4; ++r) {
      const int ql = lg * 4 + r;
      const float inv = invs[w * 16 + ql];
      const int d = dt * 16 + l15;
      O[(((size_t)(i * 4 + b) * 64 + w * 16 + ql) * 1024) + h * 64 + d] =
          f2bf(o[dt][r] * inv);
    }
}

// ---------------- layer norm over rows of 1024 ------------------------------
__global__ __launch_bounds__(256) void ln_kernel(const float* __restrict__ X,
                                                 const float* __restrict__ g,
                                                 const float* __restrict__ be,
                                                 float* __restrict__ Y,
                                                 unsigned short* __restrict__ Yb) {
  __shared__ float rs[8];
  int row = blockIdx.x, tid = threadIdx.x;
  const float* x = X + (size_t)row * 1024 + tid * 4;
  float4 v = *(const float4*)x;
  float s = v.x + v.y + v.z + v.w;
  float s2 = v.x * v.x + v.y * v.y + v.z * v.z + v.w * v.w;
#pragma unroll
  for (int off = 32; off > 0; off >>= 1) {
    s += __shfl_down(s, off);
    s2 += __shfl_down(s2, off);
  }
  int lane = tid & 63, wid = tid >> 6;
  if (lane == 0) { rs[wid * 2] = s; rs[wid * 2 + 1] = s2; }
  __syncthreads();
  if (tid == 0) {
    float aa = rs[0] + rs[2] + rs[4] + rs[6];
    float cc = rs[1] + rs[3] + rs[5] + rs[7];
    rs[0] = aa; rs[1] = cc;
  }
  __syncthreads();
  float mu = rs[0] * (1.0f / 1024.0f);
  float var = rs[1] * (1.0f / 1024.0f) - mu * mu;
  var = fmaxf(var, 0.f);
  float inv = 1.0f / sqrtf(var + 1e-6f);
  float4 gv = *(const float4*)(g + tid * 4);
  float4 bv = *(const float4*)(be + tid * 4);
  float4 o;
  o.x = (v.x - mu) * inv * gv.x + bv.x;
  o.y = (v.y - mu) * inv * gv.y + bv.y;
  o.z = (v.z - mu) * inv * gv.z + bv.z;
  o.w = (v.w - mu) * inv * gv.w + bv.w;
  *(float4*)(Y + (size_t)row * 1024 + tid * 4) = o;
  if (Yb) {
    u16x4 ob;
    ob.x = f2bf(o.x); ob.y = f2bf(o.y); ob.z = f2bf(o.z); ob.w = f2bf(o.w);
    *(u16x4*)(Yb + (size_t)row * 1024 + tid * 4) = ob;
  }
}

// ---------------------------------------------------------------------------
extern "C" void kernel_launch(void* const* d_in, const int* in_sizes, int n_in,
                              void* d_out, int out_size, void* d_ws,
                              size_t ws_size, hipStream_t stream) {
  const float* in_t = (const float*)d_in[0];
  const float* in_a = (const float*)d_in[1];
  const float* in_v = (const float*)d_in[2];
  const int* mask = (const int*)d_in[3];
  const float* w_qs = (const float*)d_in[4];
  const float* w_ks = (const float*)d_in[5];
  const float* w_vs = (const float*)d_in[6];
  const float* w_ds0 = (const float*)d_in[7];
  const float* w_ds1 = (const float*)d_in[8];
  const float* dc_w1 = (const float*)d_in[9];
  const float* dc_b1 = (const float*)d_in[10];
  const float* dc_w2 = (const float*)d_in[11];
  const float* dc_b2 = (const float*)d_in[12];
  const float* w_fc = (const float*)d_in[13];
  const float* ln1_g = (const float*)d_in[14];
  const float* ln1_b = (const float*)d_in[15];
  const float* ffn_w1 = (const float*)d_in[16];
  const float* ffn_b1 = (const float*)d_in[17];
  const float* ffn_w2 = (const float*)d_in[18];
  const float* ffn_b2 = (const float*)d_in[19];
  const float* ln2_g = (const float*)d_in[20];
  const float* ln2_b = (const float*)d_in[21];
  float* out = (float*)d_out;

  char* p = (char*)d_ws;
  auto alloc = [&](size_t bytes) {
    char* r = p;
    p += (bytes + 255) & ~(size_t)255;
    return r;
  };
  unsigned short* WQS = (unsigned short*)alloc(1024 * 1024 * 2);
  unsigned short* WKS = (unsigned short*)alloc(1024 * 1024 * 2);
  unsigned short* WVS = (unsigned short*)alloc(1024 * 1024 * 2);
  unsigned short* WD0 = (unsigned short*)alloc(1024 * 1024 * 2);
  unsigned short* WD1 = (unsigned short*)alloc(1024 * 1024 * 2);
  unsigned short* WW1 = (unsigned short*)alloc((size_t)2048 * 2048 * 2);
  unsigned short* WFC = (unsigned short*)alloc(1024 * 1024 * 2);
  unsigned short* WF1 = (unsigned short*)alloc((size_t)4096 * 1024 * 2);
  unsigned short* WF2 = (unsigned short*)alloc((size_t)1024 * 4096 * 2);
  float* Xf = (float*)alloc((size_t)786432 * 4);
  unsigned short* Xb = (unsigned short*)alloc((size_t)786432 * 2);
  unsigned short* Qb = (unsigned short*)alloc((size_t)786432 * 2);
  unsigned short* Kb = (unsigned short*)alloc((size_t)786432 * 2);
  unsigned short* Vb = (unsigned short*)alloc((size_t)786432 * 2);
  unsigned short* D0b = (unsigned short*)alloc((size_t)786432 * 2);
  unsigned short* D1b = (unsigned short*)alloc((size_t)786432 * 2);
  float* DEC = (float*)alloc((size_t)147456 * 4);
  unsigned short* OATTb = (unsigned short*)alloc((size_t)786432 * 2);
  float2* PART = (float2*)alloc((size_t)16 * 147456 * 8);  // 18.9 MB partials
  char* U = alloc((size_t)14155776);
  float* A0f = (float*)U;
  float* A1f = (float*)(U + (size_t)6291456);
  float* F2 = (float*)U;
  float* O1f = (float*)(U + (size_t)3145728);
  unsigned short* O1b = (unsigned short*)(U + (size_t)6291456);
  unsigned short* Hfb = (unsigned short*)(U + (size_t)7864320);

  dim3 blk(256);

  WtJobs jobs;
  int ts = 0;
  auto setjob = [&](int idx, const float* s, unsigned short* d, int K, int N) {
    jobs.j[idx].src = s; jobs.j[idx].dst = d;
    jobs.j[idx].K = K; jobs.j[idx].N = N; jobs.j[idx].tstart = ts;
    ts += (K / 32) * (N / 32);
  };
  setjob(0, w_qs, WQS, 1024, 1024);
  setjob(1, w_ks, WKS, 1024, 1024);
  setjob(2, w_vs, WVS, 1024, 1024);
  setjob(3, w_ds0, WD0, 1024, 1024);
  setjob(4, w_ds1, WD1, 1024, 1024);
  setjob(5, dc_w1, WW1, 2048, 2048);
  setjob(6, w_fc, WFC, 1024, 1024);
  setjob(7, ffn_w1, WF1, 1024, 4096);
  setjob(8, ffn_w2, WF2, 4096, 1024);
  wt_transpose<<<dim3(ts), blk, 0, stream>>>(jobs);

  concat3<<<dim3(768), blk, 0, stream>>>((const float4*)in_t,
                                         (const float4*)in_a,
                                         (const float4*)in_v,
                                         (float4*)Xf, (u16x4*)Xb);

  GemmBatch proj{};
  unsigned short* pouts[5] = {Qb, Kb, Vb, D0b, D1b};
  const unsigned short* pws[5] = {WQS, WKS, WVS, WD0, WD1};
  for (int z = 0; z < 5; ++z) {
    proj.op[z].A = Xb; proj.op[z].B = pws[z];
    proj.op[z].bias = nullptr; proj.op[z].add = nullptr;
    proj.op[z].Cf = nullptr; proj.op[z].Cb = pouts[z];
    proj.op[z].lda = 1024; proj.op[z].ldb = 1024;
    proj.op[z].N = 1024; proj.op[z].K = 1024; proj.op[z].relu = 0;
  }
  gemm_mfma<<<dim3(16, 12, 5), blk, 0, stream>>>(proj);

  GemmBatch pair{};
  pair.op[0].A = D0b; pair.op[0].B = WW1 + 1024;
  pair.op[0].bias = nullptr; pair.op[0].add = nullptr;
  pair.op[0].Cf = A0f; pair.op[0].Cb = nullptr;
  pair.op[0].lda = 1024; pair.op[0].ldb = 2048;
  pair.op[0].N = 2048; pair.op[0].K = 1024; pair.op[0].relu = 0;
  pair.op[1] = pair.op[0];
  pair.op[1].A = D1b; pair.op[1].B = WW1; pair.op[1].bias = dc_b1;
  pair.op[1].Cf = A1f;
  gemm_mfma<<<dim3(32, 12, 2), blk, 0, stream>>>(pair);

  decision_part<<<dim3(16, 4, 9), blk, 0, stream>>>(A1f, A0f, dc_w2, PART);
  decision_reduce<<<dim3(576), blk, 0, stream>>>(PART, dc_b2, DEC);

  attn_mfma<<<dim3(16, 4, 3), blk, 0, stream>>>(Qb, Kb, Vb, DEC, mask, OATTb);

  GemmBatch fc{};
  fc.op[0].A = OATTb; fc.op[0].B = WFC;
  fc.op[0].bias = nullptr; fc.op[0].add = Xf;
  fc.op[0].Cf = F2; fc.op[0].Cb = nullptr;
  fc.op[0].lda = 1024; fc.op[0].ldb = 1024;
  fc.op[0].N = 1024; fc.op[0].K = 1024; fc.op[0].relu = 0;
  gemm_mfma<<<dim3(16, 12, 1), blk, 0, stream>>>(fc);

  ln_kernel<<<dim3(768), blk, 0, stream>>>(F2, ln1_g, ln1_b, O1f, O1b);

  GemmBatch f1{};
  f1.op[0].A = O1b; f1.op[0].B = WF1;
  f1.op[0].bias = ffn_b1; f1.op[0].add = nullptr;
  f1.op[0].Cf = nullptr; f1.op[0].Cb = Hfb;
  f1.op[0].lda = 1024; f1.op[0].ldb = 1024;
  f1.op[0].N = 4096; f1.op[0].K = 1024; f1.op[0].relu = 1;
  gemm_mfma<<<dim3(64, 12, 1), blk, 0, stream>>>(f1);

  GemmBatch f2{};
  f2.op[0].A = Hfb; f2.op[0].B = WF2;
  f2.op[0].bias = ffn_b2; f2.op[0].add = O1f;
  f2.op[0].Cf = F2; f2.op[0].Cb = nullptr;
  f2.op[0].lda = 4096; f2.op[0].ldb = 4096;
  f2.op[0].N = 1024; f2.op[0].K = 4096; f2.op[0].relu = 0;
  gemm_mfma<<<dim3(16, 12, 1), blk, 0, stream>>>(f2);

  ln_kernel<<<dim3(768), blk, 0, stream>>>(F2, ln2_g, ln2_b, out, nullptr);
}

// Round 6
// 191.994 us; speedup vs baseline: 4.9735x; 1.0339x over previous
//
#include <hip/hip_runtime.h>
#include <math.h>

// ---------------------------------------------------------------------------
// MMModel bf16-MFMA implementation. B=4, L=64, DM=1024, H=16, DK=DV=64,
// D=1024, DI=4096, nm=3. Row convention: row = (i*B + b)*L + l  (768 rows).
// ---------------------------------------------------------------------------

#define NEGV (-1000000000.0f)

typedef float f32x4 __attribute__((ext_vector_type(4)));
typedef short short8 __attribute__((ext_vector_type(8)));
typedef unsigned short u16x8 __attribute__((ext_vector_type(8)));
typedef unsigned short u16x4 __attribute__((ext_vector_type(4)));

typedef __attribute__((address_space(1))) const void glob_cv;
typedef __attribute__((address_space(3))) void lds_v;

static __device__ __forceinline__ unsigned short f2bf(float f) {
  unsigned u = __builtin_bit_cast(unsigned, f);
  u += 0x7fffu + ((u >> 16) & 1u);
  return (unsigned short)(u >> 16);
}
static __device__ __forceinline__ float bf2f(unsigned short h) {
  return __builtin_bit_cast(float, ((unsigned)h) << 16);
}

// async global->LDS, 16B per lane. Per-lane global addr; LDS base is taken
// from lane 0 (wave-uniform) + lane*16 by HW, and we pass per-lane ptrs that
// match that layout exactly (linear).
static __device__ __forceinline__ void gload16(const unsigned short* g,
                                               unsigned short* l) {
  __builtin_amdgcn_global_load_lds((glob_cv*)g, (lds_v*)l, 16, 0, 0);
}

// ---------------- concat inputs into Xf[768][1024] f32 + Xb bf16 ------------
__global__ __launch_bounds__(256) void concat3(const float4* __restrict__ t,
                                               const float4* __restrict__ a,
                                               const float4* __restrict__ v,
                                               float4* __restrict__ Xf,
                                               u16x4* __restrict__ Xb) {
  int id = blockIdx.x * 256 + threadIdx.x;  // 768*256 float4s
  int m = id >> 16;
  int off = id & 65535;
  const float4* s = (m == 0) ? t : (m == 1) ? a : v;
  float4 val = s[off];
  Xf[id] = val;
  u16x4 bb;
  bb.x = f2bf(val.x); bb.y = f2bf(val.y);
  bb.z = f2bf(val.z); bb.w = f2bf(val.w);
  Xb[id] = bb;
}

// ---------------- weight transpose + f32->bf16: dst[n][k] = src[k][n] -------
struct WtJob { const float* src; unsigned short* dst; int K, N, tstart; };
struct WtJobs { WtJob j[9]; };

__global__ __launch_bounds__(256) void wt_transpose(WtJobs jobs) {
  __shared__ float Ls[32][33];
  int ji = 0;
#pragma unroll
  for (int t = 1; t < 9; ++t)
    if ((int)blockIdx.x >= jobs.j[t].tstart) ji = t;
  const WtJob jb = jobs.j[ji];
  int local = blockIdx.x - jb.tstart;
  int ntx = jb.N >> 5;
  int tk = local / ntx, tn = local - tk * ntx;
  const int tid = threadIdx.x;
  const int r = tid >> 3, c = (tid & 7) * 4;
  float4 v = *(const float4*)(jb.src + (size_t)(tk * 32 + r) * jb.N + tn * 32 + c);
  Ls[r][c + 0] = v.x; Ls[r][c + 1] = v.y;
  Ls[r][c + 2] = v.z; Ls[r][c + 3] = v.w;
  __syncthreads();
  u16x4 o;
  o.x = f2bf(Ls[c + 0][r]);
  o.y = f2bf(Ls[c + 1][r]);
  o.z = f2bf(Ls[c + 2][r]);
  o.w = f2bf(Ls[c + 3][r]);
  *(u16x4*)(jb.dst + (size_t)(tn * 32 + r) * jb.K + tk * 32 + c) = o;
}

// ---------------- bf16 MFMA GEMM (64M x 128N tile, global_load_lds) ---------
// C[M=768][N] = A[768][K](bf16) * Wt[N][K](bf16)^T  (+bias)(+add f32)(relu)
// 256 threads = 4 waves (2M x 2N); per wave 32x64 output (acc 2x4 f32x4).
// BK=64. LDS: As[64][64] + Bs[128][64] bf16 linear = 24 KB.
struct GemmOp {
  const unsigned short* A;
  const unsigned short* B;   // Wt, row n, col k, stride ldb
  const float* bias;         // [N] or null
  const float* add;          // [768][N] f32 or null
  float* Cf;                 // or null
  unsigned short* Cb;        // or null
  int lda, ldb, N, K, relu;
};
struct GemmBatch { GemmOp op[5]; };

__global__ __launch_bounds__(256, 2) void gemm_mfma(GemmBatch batch) {
  const GemmOp g = batch.op[blockIdx.z];
  __shared__ unsigned short As[64 * 64];    // [m][k] linear
  __shared__ unsigned short Bs[128 * 64];   // [n][k] linear
  const int bm = blockIdx.y * 64, bn = blockIdx.x * 128;
  const int tid = threadIdx.x;
  const int l = tid & 63, w = tid >> 6;
  const int wr = (w >> 1) * 32, wc = (w & 1) * 64;
  const int lr = l & 15, lg = l >> 4;
  const int crow = l >> 3, ccol = (l & 7) * 8;  // within 8-row staging chunk
  f32x4 acc[2][4] = {};
  for (int k0 = 0; k0 < g.K; k0 += 64) {
    __syncthreads();  // previous compute reads done; LDS reusable
#pragma unroll
    for (int c = 0; c < 2; ++c) {           // A: 8 chunks of 8 rows
      const int ch = w * 2 + c;
      gload16(g.A + (size_t)(bm + ch * 8 + crow) * g.lda + k0 + ccol,
              &As[ch * 512 + l * 8]);
    }
#pragma unroll
    for (int c = 0; c < 4; ++c) {           // B: 16 chunks of 8 rows
      const int ch = w * 4 + c;
      gload16(g.B + (size_t)(bn + ch * 8 + crow) * g.ldb + k0 + ccol,
              &Bs[ch * 512 + l * 8]);
    }
    __syncthreads();  // vmcnt(0) drained by compiler before barrier
#pragma unroll
    for (int ks = 0; ks < 2; ++ks) {
      short8 af[2], bf[4];
#pragma unroll
      for (int i = 0; i < 2; ++i)
        af[i] = *(const short8*)&As[(wr + i * 16 + lr) * 64 + ks * 32 + lg * 8];
#pragma unroll
      for (int j = 0; j < 4; ++j)
        bf[j] = *(const short8*)&Bs[(wc + j * 16 + lr) * 64 + ks * 32 + lg * 8];
#pragma unroll
      for (int i = 0; i < 2; ++i)
#pragma unroll
        for (int j = 0; j < 4; ++j)
          acc[i][j] =
              __builtin_amdgcn_mfma_f32_16x16x32_bf16(af[i], bf[j], acc[i][j], 0, 0, 0);
    }
  }
  // epilogue: C/D layout col=lane&15, row=(lane>>4)*4+reg
#pragma unroll
  for (int j = 0; j < 4; ++j) {
    const int col = bn + wc + j * 16 + lr;
    const float bv = g.bias ? g.bias[col] : 0.0f;
#pragma unroll
    for (int i = 0; i < 2; ++i) {
#pragma unroll
      for (int ii = 0; ii < 4; ++ii) {
        const int row = bm + wr + i * 16 + lg * 4 + ii;
        float v = acc[i][j][ii] + bv;
        if (g.add) v += g.add[(size_t)row * g.N + col];
        if (g.relu) v = fmaxf(v, 0.0f);
        if (g.Cf) g.Cf[(size_t)row * g.N + col] = v;
        if (g.Cb) g.Cb[(size_t)row * g.N + col] = f2bf(v);
      }
    }
  }
}

// ---------------- FFN2 k-split reduce: F2 = sum(P[0..3]) + bias + add -------
__global__ __launch_bounds__(256) void fsum(const float* __restrict__ P,
                                            const float* __restrict__ bias,
                                            const float* __restrict__ add,
                                            float* __restrict__ out) {
  const int row = blockIdx.x;
  const int c = threadIdx.x * 4;
  const size_t o = (size_t)row * 1024 + c;
  float4 p0 = *(const float4*)(P + o);
  float4 p1 = *(const float4*)(P + 786432 + o);
  float4 p2 = *(const float4*)(P + 2 * 786432 + o);
  float4 p3 = *(const float4*)(P + 3 * 786432 + o);
  float4 bs = *(const float4*)(bias + c);
  float4 ad = *(const float4*)(add + o);
  float4 r;
  r.x = ((p0.x + p1.x) + (p2.x + p3.x)) + bs.x + ad.x;
  r.y = ((p0.y + p1.y) + (p2.y + p3.y)) + bs.y + ad.y;
  r.z = ((p0.z + p1.z) + (p2.z + p3.z)) + bs.z + ad.z;
  r.w = ((p0.w + p1.w) + (p2.w + p3.w)) + bs.w + ad.w;
  *(float4*)(out + o) = r;
}

// ---------------- decision gate, pass 1: partial sums -----------------------
__global__ __launch_bounds__(256) void decision_part(
    const float* __restrict__ A1, const float* __restrict__ A0,
    const float* __restrict__ w2, float2* __restrict__ PART) {
  __shared__ float2 sA1[64][34];
  __shared__ float2 sA0[64][34];
  __shared__ float2 sW2[64];
  const int ds = blockIdx.x;
  const int b = blockIdx.y, pp = blockIdx.z;
  const int i = pp / 3, j = pp % 3;
  const int tid = threadIdx.x;
  const int tq = tid >> 4, tk = tid & 15;
  const float* a1base = A1 + ((size_t)(j * 4 + b) * 64) * 2048 + ds * 128;
  const float* a0base = A0 + ((size_t)(i * 4 + b) * 64) * 2048 + ds * 128;
  float acc[4][4][2] = {};
  for (int c = 0; c < 2; ++c) {
    __syncthreads();
#pragma unroll
    for (int p16 = 0; p16 < 4; ++p16) {
      const int row = p16 * 16 + (tid >> 4);
      const int col = (tid & 15) * 4;
      float4 v1 = *(const float4*)(a1base + (size_t)row * 2048 + c * 64 + col);
      float4 v0 = *(const float4*)(a0base + (size_t)row * 2048 + c * 64 + col);
      float2* d1 = &sA1[row][(tid & 15) * 2];
      d1[0].x = v1.x; d1[0].y = v1.y; d1[1].x = v1.z; d1[1].y = v1.w;
      float2* d0 = &sA0[row][(tid & 15) * 2];
      d0[0].x = v0.x; d0[0].y = v0.y; d0[1].x = v0.z; d0[1].y = v0.w;
    }
    if (tid < 64)
      sW2[tid] = *(const float2*)(w2 + (size_t)(ds * 128 + c * 64 + tid) * 2);
    __syncthreads();
#pragma unroll 4
    for (int s = 0; s < 32; ++s) {
      float2 a1v[4], a0v[4];
#pragma unroll
      for (int r = 0; r < 4; ++r) {
        a1v[r] = sA1[tq + 16 * r][s];
        a0v[r] = sA0[tk + 16 * r][s];
      }
      const float2 wA = sW2[2 * s], wB = sW2[2 * s + 1];
#pragma unroll
      for (int qr = 0; qr < 4; ++qr)
#pragma unroll
        for (int kr = 0; kr < 4; ++kr) {
          float v0 = fmaxf(a1v[qr].x + a0v[kr].x, 0.f);
          acc[qr][kr][0] = fmaf(v0, wA.x, acc[qr][kr][0]);
          acc[qr][kr][1] = fmaf(v0, wA.y, acc[qr][kr][1]);
          float v1 = fmaxf(a1v[qr].y + a0v[kr].y, 0.f);
          acc[qr][kr][0] = fmaf(v1, wB.x, acc[qr][kr][0]);
          acc[qr][kr][1] = fmaf(v1, wB.y, acc[qr][kr][1]);
        }
    }
  }
  float2* outp = PART + (size_t)ds * 147456 + ((size_t)pp * 4 + b) * 4096;
#pragma unroll
  for (int qr = 0; qr < 4; ++qr)
#pragma unroll
    for (int kr = 0; kr < 4; ++kr) {
      float2 o;
      o.x = acc[qr][kr][0];
      o.y = acc[qr][kr][1];
      outp[(tq + 16 * qr) * 64 + (tk + 16 * kr)] = o;
    }
}

// ---------------- decision gate, pass 2: reduce + compare -------------------
__global__ __launch_bounds__(256) void decision_reduce(
    const float2* __restrict__ PART, const float* __restrict__ b2,
    float* __restrict__ DEC) {
  const int out = blockIdx.x * 256 + threadIdx.x;
  float acc0 = 0.f, acc1 = 0.f;
#pragma unroll
  for (int s = 0; s < 16; ++s) {
    float2 v = PART[(size_t)s * 147456 + out];
    acc0 += v.x;
    acc1 += v.y;
  }
  float l0 = acc0 + b2[0], l1 = acc1 + b2[1];
  DEC[out] = (l1 > l0) ? NEGV : 0.f;
}

// ---------------- MFMA attention (race-fixed: full barrier discipline) ------
__global__ __launch_bounds__(256) void attn_mfma(
    const unsigned short* __restrict__ Qa, const unsigned short* __restrict__ Ka,
    const unsigned short* __restrict__ Va, const float* __restrict__ DEC,
    const int* __restrict__ mask, unsigned short* __restrict__ O) {
  __shared__ __align__(16) char sm[49408];
  char* KsP = sm;
  char* Vt = sm + 24576;
  float* invs = (float*)(sm + 49152);

  const int h = blockIdx.x, b = blockIdx.y, i = blockIdx.z;
  const int tid = threadIdx.x;
  const int l = tid & 63, w = tid >> 6;
  const int l15 = l & 15, lg = l >> 4;

#pragma unroll
  for (int rep = 0; rep < 6; ++rep) {
    int flat = rep * 256 + tid;
    int key = flat >> 3, c8 = flat & 7;
    int j = key >> 6, kl = key & 63;
    const size_t rowoff = (((size_t)(j * 4 + b) * 64 + kl) * 1024) + h * 64 + c8 * 8;
    u16x8 kv = *(const u16x8*)(Ka + rowoff);
    *(u16x8*)(KsP + ((key * 128 + c8 * 16) ^ ((key & 7) << 4))) = kv;
    u16x8 vv = *(const u16x8*)(Va + rowoff);
#pragma unroll
    for (int jj = 0; jj < 8; ++jj) {
      int d = c8 * 8 + jj;
      *(unsigned short*)(Vt + ((d * 384 + key * 2) ^ ((d & 7) << 4))) = vv[jj];
    }
  }

  const int qg = w * 16 + l15;
  const unsigned short* qsrc =
      Qa + (((size_t)(i * 4 + b) * 64 + qg) * 1024) + h * 64 + lg * 8;
  short8 qf0 = *(const short8*)(qsrc);
  short8 qf1 = *(const short8*)(qsrc + 32);

  __syncthreads();  // (1)

  f32x4 s[12];
#pragma unroll
  for (int t = 0; t < 12; ++t) {
    const int key = t * 16 + l15;
    const int swz = (key & 7) << 4;
    short8 kf0 = *(const short8*)(KsP + ((key * 128 + 0 + lg * 16) ^ swz));
    short8 kf1 = *(const short8*)(KsP + ((key * 128 + 64 + lg * 16) ^ swz));
    f32x4 z = {0.f, 0.f, 0.f, 0.f};
    z = __builtin_amdgcn_mfma_f32_16x16x32_bf16(kf0, qf0, z, 0, 0, 0);
    z = __builtin_amdgcn_mfma_f32_16x16x32_bf16(kf1, qf1, z, 0, 0, 0);
    s[t] = z;
  }

  int mk[4][4];
#pragma unroll
  for (int t4 = 0; t4 < 4; ++t4)
#pragma unroll
    for (int r = 0; r < 4; ++r)
      mk[t4][r] = mask[((size_t)b * 64 + qg) * 64 + t4 * 16 + lg * 4 + r];

  float mx = -3.0e38f;
#pragma unroll
  for (int t = 0; t < 12; ++t) {
    const float* dbase =
        DEC + (((size_t)(i * 3 + (t >> 2)) * 4 + b) * 4096) + qg * 64;
#pragma unroll
    for (int r = 0; r < 4; ++r) {
      const int kl = (t & 3) * 16 + lg * 4 + r;
      float sv = s[t][r] * 0.125f + dbase[kl];
      if (mk[t & 3][r] == 0) sv = NEGV;
      s[t][r] = sv;
      mx = fmaxf(mx, sv);
    }
  }
  mx = fmaxf(mx, __shfl_xor(mx, 16));
  mx = fmaxf(mx, __shfl_xor(mx, 32));
  float sum = 0.f;
#pragma unroll
  for (int t = 0; t < 12; ++t)
#pragma unroll
    for (int r = 0; r < 4; ++r) {
      float p = __expf(s[t][r] - mx);
      s[t][r] = p;
      sum += p;
    }
  sum += __shfl_xor(sum, 16);
  sum += __shfl_xor(sum, 32);
  if (l < 16) invs[w * 16 + l] = 1.0f / sum;

  __syncthreads();  // (2)

  char* Pmy = KsP + w * 6144;
  const int pswz = (l15 & 7) << 4;

#pragma unroll
  for (int t = 0; t < 12; ++t)
#pragma unroll
    for (int r = 0; r < 4; ++r) {
      const int key = t * 16 + lg * 4 + r;
      *(unsigned short*)(Pmy + ((l15 * 384 + key * 2) ^ pswz)) = f2bf(s[t][r]);
    }
  __syncthreads();  // (3)

  f32x4 o[4] = {};
#pragma unroll
  for (int kc = 0; kc < 6; ++kc) {
    short8 pf = *(const short8*)(Pmy + ((l15 * 384 + kc * 64 + lg * 16) ^ pswz));
#pragma unroll
    for (int dt = 0; dt < 4; ++dt) {
      const int d = dt * 16 + l15;
      short8 vf = *(const short8*)(Vt + ((d * 384 + kc * 64 + lg * 16) ^ ((d & 7) << 4)));
      o[dt] = __builtin_amdgcn_mfma_f32_16x16x32_bf16(pf, vf, o[dt], 0, 0, 0);
    }
  }
  __syncthreads();  // (4)

#pragma unroll
  for (int t = 0; t < 12; ++t)
#pragma unroll
    for (int r = 0; r < 4; ++r) {
      const int key = t * 16 + lg * 4 + r;
      float p = s[t][r];
      float lo = p - bf2f(f2bf(p));
      *(unsigned short*)(Pmy + ((l15 * 384 + key * 2) ^ pswz)) = f2bf(lo);
    }
  __syncthreads();  // (5)

#pragma unroll
  for (int kc = 0; kc < 6; ++kc) {
    short8 pf = *(const short8*)(Pmy + ((l15 * 384 + kc * 64 + lg * 16) ^ pswz));
#pragma unroll
    for (int dt = 0; dt < 4; ++dt) {
      const int d = dt * 16 + l15;
      short8 vf = *(const short8*)(Vt + ((d * 384 + kc * 64 + lg * 16) ^ ((d & 7) << 4)));
      o[dt] = __builtin_amdgcn_mfma_f32_16x16x32_bf16(pf, vf, o[dt], 0, 0, 0);
    }
  }

#pragma unroll
  for (int dt = 0; dt < 4; ++dt)
#pragma unroll
    for (int r = 0; r < 4; ++r) {
      const int ql = lg * 4 + r;
      const float inv = invs[w * 16 + ql];
      const int d = dt * 16 + l15;
      O[(((size_t)(i * 4 + b) * 64 + w * 16 + ql) * 1024) + h * 64 + d] =
          f2bf(o[dt][r] * inv);
    }
}

// ---------------- layer norm over rows of 1024 ------------------------------
__global__ __launch_bounds__(256) void ln_kernel(const float* __restrict__ X,
                                                 const float* __restrict__ g,
                                                 const float* __restrict__ be,
                                                 float* __restrict__ Y,
                                                 unsigned short* __restrict__ Yb) {
  __shared__ float rs[8];
  int row = blockIdx.x, tid = threadIdx.x;
  const float* x = X + (size_t)row * 1024 + tid * 4;
  float4 v = *(const float4*)x;
  float s = v.x + v.y + v.z + v.w;
  float s2 = v.x * v.x + v.y * v.y + v.z * v.z + v.w * v.w;
#pragma unroll
  for (int off = 32; off > 0; off >>= 1) {
    s += __shfl_down(s, off);
    s2 += __shfl_down(s2, off);
  }
  int lane = tid & 63, wid = tid >> 6;
  if (lane == 0) { rs[wid * 2] = s; rs[wid * 2 + 1] = s2; }
  __syncthreads();
  if (tid == 0) {
    float aa = rs[0] + rs[2] + rs[4] + rs[6];
    float cc = rs[1] + rs[3] + rs[5] + rs[7];
    rs[0] = aa; rs[1] = cc;
  }
  __syncthreads();
  float mu = rs[0] * (1.0f / 1024.0f);
  float var = rs[1] * (1.0f / 1024.0f) - mu * mu;
  var = fmaxf(var, 0.f);
  float inv = 1.0f / sqrtf(var + 1e-6f);
  float4 gv = *(const float4*)(g + tid * 4);
  float4 bv = *(const float4*)(be + tid * 4);
  float4 o;
  o.x = (v.x - mu) * inv * gv.x + bv.x;
  o.y = (v.y - mu) * inv * gv.y + bv.y;
  o.z = (v.z - mu) * inv * gv.z + bv.z;
  o.w = (v.w - mu) * inv * gv.w + bv.w;
  *(float4*)(Y + (size_t)row * 1024 + tid * 4) = o;
  if (Yb) {
    u16x4 ob;
    ob.x = f2bf(o.x); ob.y = f2bf(o.y); ob.z = f2bf(o.z); ob.w = f2bf(o.w);
    *(u16x4*)(Yb + (size_t)row * 1024 + tid * 4) = ob;
  }
}

// ---------------------------------------------------------------------------
extern "C" void kernel_launch(void* const* d_in, const int* in_sizes, int n_in,
                              void* d_out, int out_size, void* d_ws,
                              size_t ws_size, hipStream_t stream) {
  const float* in_t = (const float*)d_in[0];
  const float* in_a = (const float*)d_in[1];
  const float* in_v = (const float*)d_in[2];
  const int* mask = (const int*)d_in[3];
  const float* w_qs = (const float*)d_in[4];
  const float* w_ks = (const float*)d_in[5];
  const float* w_vs = (const float*)d_in[6];
  const float* w_ds0 = (const float*)d_in[7];
  const float* w_ds1 = (const float*)d_in[8];
  const float* dc_w1 = (const float*)d_in[9];
  const float* dc_b1 = (const float*)d_in[10];
  const float* dc_w2 = (const float*)d_in[11];
  const float* dc_b2 = (const float*)d_in[12];
  const float* w_fc = (const float*)d_in[13];
  const float* ln1_g = (const float*)d_in[14];
  const float* ln1_b = (const float*)d_in[15];
  const float* ffn_w1 = (const float*)d_in[16];
  const float* ffn_b1 = (const float*)d_in[17];
  const float* ffn_w2 = (const float*)d_in[18];
  const float* ffn_b2 = (const float*)d_in[19];
  const float* ln2_g = (const float*)d_in[20];
  const float* ln2_b = (const float*)d_in[21];
  float* out = (float*)d_out;

  char* p = (char*)d_ws;
  auto alloc = [&](size_t bytes) {
    char* r = p;
    p += (bytes + 255) & ~(size_t)255;
    return r;
  };
  unsigned short* WQS = (unsigned short*)alloc(1024 * 1024 * 2);
  unsigned short* WKS = (unsigned short*)alloc(1024 * 1024 * 2);
  unsigned short* WVS = (unsigned short*)alloc(1024 * 1024 * 2);
  unsigned short* WD0 = (unsigned short*)alloc(1024 * 1024 * 2);
  unsigned short* WD1 = (unsigned short*)alloc(1024 * 1024 * 2);
  unsigned short* WW1 = (unsigned short*)alloc((size_t)2048 * 2048 * 2);
  unsigned short* WFC = (unsigned short*)alloc(1024 * 1024 * 2);
  unsigned short* WF1 = (unsigned short*)alloc((size_t)4096 * 1024 * 2);
  unsigned short* WF2 = (unsigned short*)alloc((size_t)1024 * 4096 * 2);
  float* Xf = (float*)alloc((size_t)786432 * 4);
  unsigned short* Xb = (unsigned short*)alloc((size_t)786432 * 2);
  unsigned short* Qb = (unsigned short*)alloc((size_t)786432 * 2);
  unsigned short* Kb = (unsigned short*)alloc((size_t)786432 * 2);
  unsigned short* Vb = (unsigned short*)alloc((size_t)786432 * 2);
  unsigned short* D0b = (unsigned short*)alloc((size_t)786432 * 2);
  unsigned short* D1b = (unsigned short*)alloc((size_t)786432 * 2);
  float* DEC = (float*)alloc((size_t)147456 * 4);
  unsigned short* OATTb = (unsigned short*)alloc((size_t)786432 * 2);
  float2* PART = (float2*)alloc((size_t)16 * 147456 * 8);  // 18.9 MB partials
  float* FPART = (float*)PART;  // reused after decision for FFN2 k-split (12.6 MB)
  char* U = alloc((size_t)14155776);
  float* A0f = (float*)U;
  float* A1f = (float*)(U + (size_t)6291456);
  float* F2 = (float*)U;
  float* O1f = (float*)(U + (size_t)3145728);
  unsigned short* O1b = (unsigned short*)(U + (size_t)6291456);
  unsigned short* Hfb = (unsigned short*)(U + (size_t)7864320);

  dim3 blk(256);

  WtJobs jobs;
  int ts = 0;
  auto setjob = [&](int idx, const float* s, unsigned short* d, int K, int N) {
    jobs.j[idx].src = s; jobs.j[idx].dst = d;
    jobs.j[idx].K = K; jobs.j[idx].N = N; jobs.j[idx].tstart = ts;
    ts += (K / 32) * (N / 32);
  };
  setjob(0, w_qs, WQS, 1024, 1024);
  setjob(1, w_ks, WKS, 1024, 1024);
  setjob(2, w_vs, WVS, 1024, 1024);
  setjob(3, w_ds0, WD0, 1024, 1024);
  setjob(4, w_ds1, WD1, 1024, 1024);
  setjob(5, dc_w1, WW1, 2048, 2048);
  setjob(6, w_fc, WFC, 1024, 1024);
  setjob(7, ffn_w1, WF1, 1024, 4096);
  setjob(8, ffn_w2, WF2, 4096, 1024);
  wt_transpose<<<dim3(ts), blk, 0, stream>>>(jobs);

  concat3<<<dim3(768), blk, 0, stream>>>((const float4*)in_t,
                                         (const float4*)in_a,
                                         (const float4*)in_v,
                                         (float4*)Xf, (u16x4*)Xb);

  GemmBatch proj{};
  unsigned short* pouts[5] = {Qb, Kb, Vb, D0b, D1b};
  const unsigned short* pws[5] = {WQS, WKS, WVS, WD0, WD1};
  for (int z = 0; z < 5; ++z) {
    proj.op[z].A = Xb; proj.op[z].B = pws[z];
    proj.op[z].bias = nullptr; proj.op[z].add = nullptr;
    proj.op[z].Cf = nullptr; proj.op[z].Cb = pouts[z];
    proj.op[z].lda = 1024; proj.op[z].ldb = 1024;
    proj.op[z].N = 1024; proj.op[z].K = 1024; proj.op[z].relu = 0;
  }
  gemm_mfma<<<dim3(8, 12, 5), blk, 0, stream>>>(proj);

  GemmBatch pair{};
  pair.op[0].A = D0b; pair.op[0].B = WW1 + 1024;
  pair.op[0].bias = nullptr; pair.op[0].add = nullptr;
  pair.op[0].Cf = A0f; pair.op[0].Cb = nullptr;
  pair.op[0].lda = 1024; pair.op[0].ldb = 2048;
  pair.op[0].N = 2048; pair.op[0].K = 1024; pair.op[0].relu = 0;
  pair.op[1] = pair.op[0];
  pair.op[1].A = D1b; pair.op[1].B = WW1; pair.op[1].bias = dc_b1;
  pair.op[1].Cf = A1f;
  gemm_mfma<<<dim3(16, 12, 2), blk, 0, stream>>>(pair);

  decision_part<<<dim3(16, 4, 9), blk, 0, stream>>>(A1f, A0f, dc_w2, PART);
  decision_reduce<<<dim3(576), blk, 0, stream>>>(PART, dc_b2, DEC);

  attn_mfma<<<dim3(16, 4, 3), blk, 0, stream>>>(Qb, Kb, Vb, DEC, mask, OATTb);

  GemmBatch fc{};
  fc.op[0].A = OATTb; fc.op[0].B = WFC;
  fc.op[0].bias = nullptr; fc.op[0].add = Xf;
  fc.op[0].Cf = F2; fc.op[0].Cb = nullptr;
  fc.op[0].lda = 1024; fc.op[0].ldb = 1024;
  fc.op[0].N = 1024; fc.op[0].K = 1024; fc.op[0].relu = 0;
  gemm_mfma<<<dim3(8, 12, 1), blk, 0, stream>>>(fc);

  ln_kernel<<<dim3(768), blk, 0, stream>>>(F2, ln1_g, ln1_b, O1f, O1b);

  GemmBatch f1{};
  f1.op[0].A = O1b; f1.op[0].B = WF1;
  f1.op[0].bias = ffn_b1; f1.op[0].add = nullptr;
  f1.op[0].Cf = nullptr; f1.op[0].Cb = Hfb;
  f1.op[0].lda = 1024; f1.op[0].ldb = 1024;
  f1.op[0].N = 4096; f1.op[0].K = 1024; f1.op[0].relu = 1;
  gemm_mfma<<<dim3(32, 12, 1), blk, 0, stream>>>(f1);

  // FFN2 k-split x4: partials into FPART, fixed-order reduce
  GemmBatch f2{};
  for (int z = 0; z < 4; ++z) {
    f2.op[z].A = Hfb + (size_t)z * 1024;
    f2.op[z].B = WF2 + (size_t)z * 1024;
    f2.op[z].bias = nullptr; f2.op[z].add = nullptr;
    f2.op[z].Cf = FPART + (size_t)z * 786432; f2.op[z].Cb = nullptr;
    f2.op[z].lda = 4096; f2.op[z].ldb = 4096;
    f2.op[z].N = 1024; f2.op[z].K = 1024; f2.op[z].relu = 0;
  }
  gemm_mfma<<<dim3(8, 12, 4), blk, 0, stream>>>(f2);
  fsum<<<dim3(768), blk, 0, stream>>>(FPART, ffn_b2, O1f, F2);

  ln_kernel<<<dim3(768), blk, 0, stream>>>(F2, ln2_g, ln2_b, out, nullptr);
}

// Round 7
// 185.499 us; speedup vs baseline: 5.1477x; 1.0350x over previous
//
#include <hip/hip_runtime.h>
#include <math.h>

// ---------------------------------------------------------------------------
// MMModel bf16-MFMA implementation. B=4, L=64, DM=1024, H=16, DK=DV=64,
// D=1024, DI=4096, nm=3. Row convention: row = (i*B + b)*L + l  (768 rows).
// ---------------------------------------------------------------------------

#define NEGV (-1000000000.0f)

typedef float f32x4 __attribute__((ext_vector_type(4)));
typedef float f32x2 __attribute__((ext_vector_type(2)));
typedef short short8 __attribute__((ext_vector_type(8)));
typedef unsigned short u16x8 __attribute__((ext_vector_type(8)));
typedef unsigned short u16x4 __attribute__((ext_vector_type(4)));

typedef __attribute__((address_space(1))) const void glob_cv;
typedef __attribute__((address_space(3))) void lds_v;

static __device__ __forceinline__ unsigned short f2bf(float f) {
  unsigned u = __builtin_bit_cast(unsigned, f);
  u += 0x7fffu + ((u >> 16) & 1u);
  return (unsigned short)(u >> 16);
}
static __device__ __forceinline__ float bf2f(unsigned short h) {
  return __builtin_bit_cast(float, ((unsigned)h) << 16);
}

// async global->LDS, 16B per lane (linear dest = base + lane*16).
static __device__ __forceinline__ void gload16(const unsigned short* g,
                                               unsigned short* l) {
  __builtin_amdgcn_global_load_lds((glob_cv*)g, (lds_v*)l, 16, 0, 0);
}

// ---------------- concat inputs into Xf[768][1024] f32 + Xb bf16 ------------
__global__ __launch_bounds__(256) void concat3(const float4* __restrict__ t,
                                               const float4* __restrict__ a,
                                               const float4* __restrict__ v,
                                               float4* __restrict__ Xf,
                                               u16x4* __restrict__ Xb) {
  int id = blockIdx.x * 256 + threadIdx.x;  // 768*256 float4s
  int m = id >> 16;
  int off = id & 65535;
  const float4* s = (m == 0) ? t : (m == 1) ? a : v;
  float4 val = s[off];
  Xf[id] = val;
  u16x4 bb;
  bb.x = f2bf(val.x); bb.y = f2bf(val.y);
  bb.z = f2bf(val.z); bb.w = f2bf(val.w);
  Xb[id] = bb;
}

// ---------------- weight transpose + f32->bf16: dst[n][k] = src[k][n] -------
struct WtJob { const float* src; unsigned short* dst; int K, N, tstart; };
struct WtJobs { WtJob j[9]; };

__global__ __launch_bounds__(256) void wt_transpose(WtJobs jobs) {
  __shared__ float Ls[32][33];
  int ji = 0;
#pragma unroll
  for (int t = 1; t < 9; ++t)
    if ((int)blockIdx.x >= jobs.j[t].tstart) ji = t;
  const WtJob jb = jobs.j[ji];
  int local = blockIdx.x - jb.tstart;
  int ntx = jb.N >> 5;
  int tk = local / ntx, tn = local - tk * ntx;
  const int tid = threadIdx.x;
  const int r = tid >> 3, c = (tid & 7) * 4;
  float4 v = *(const float4*)(jb.src + (size_t)(tk * 32 + r) * jb.N + tn * 32 + c);
  Ls[r][c + 0] = v.x; Ls[r][c + 1] = v.y;
  Ls[r][c + 2] = v.z; Ls[r][c + 3] = v.w;
  __syncthreads();
  u16x4 o;
  o.x = f2bf(Ls[c + 0][r]);
  o.y = f2bf(Ls[c + 1][r]);
  o.z = f2bf(Ls[c + 2][r]);
  o.w = f2bf(Ls[c + 3][r]);
  *(u16x4*)(jb.dst + (size_t)(tn * 32 + r) * jb.K + tk * 32 + c) = o;
}

// ---------------- bf16 MFMA GEMM (64M x 128N tile, global_load_lds) ---------
struct GemmOp {
  const unsigned short* A;
  const unsigned short* B;   // Wt, row n, col k, stride ldb
  const float* bias;         // [N] or null
  const float* add;          // [768][N] f32 or null
  float* Cf;                 // or null
  unsigned short* Cb;        // or null
  int lda, ldb, N, K, relu;
};
struct GemmBatch { GemmOp op[5]; };

__global__ __launch_bounds__(256, 2) void gemm_mfma(GemmBatch batch) {
  const GemmOp g = batch.op[blockIdx.z];
  __shared__ unsigned short As[64 * 64];    // [m][k] linear
  __shared__ unsigned short Bs[128 * 64];   // [n][k] linear
  const int bm = blockIdx.y * 64, bn = blockIdx.x * 128;
  const int tid = threadIdx.x;
  const int l = tid & 63, w = tid >> 6;
  const int wr = (w >> 1) * 32, wc = (w & 1) * 64;
  const int lr = l & 15, lg = l >> 4;
  const int crow = l >> 3, ccol = (l & 7) * 8;  // within 8-row staging chunk
  f32x4 acc[2][4] = {};
  for (int k0 = 0; k0 < g.K; k0 += 64) {
    __syncthreads();
#pragma unroll
    for (int c = 0; c < 2; ++c) {           // A: 8 chunks of 8 rows
      const int ch = w * 2 + c;
      gload16(g.A + (size_t)(bm + ch * 8 + crow) * g.lda + k0 + ccol,
              &As[ch * 512 + l * 8]);
    }
#pragma unroll
    for (int c = 0; c < 4; ++c) {           // B: 16 chunks of 8 rows
      const int ch = w * 4 + c;
      gload16(g.B + (size_t)(bn + ch * 8 + crow) * g.ldb + k0 + ccol,
              &Bs[ch * 512 + l * 8]);
    }
    __syncthreads();
#pragma unroll
    for (int ks = 0; ks < 2; ++ks) {
      short8 af[2], bf[4];
#pragma unroll
      for (int i = 0; i < 2; ++i)
        af[i] = *(const short8*)&As[(wr + i * 16 + lr) * 64 + ks * 32 + lg * 8];
#pragma unroll
      for (int j = 0; j < 4; ++j)
        bf[j] = *(const short8*)&Bs[(wc + j * 16 + lr) * 64 + ks * 32 + lg * 8];
#pragma unroll
      for (int i = 0; i < 2; ++i)
#pragma unroll
        for (int j = 0; j < 4; ++j)
          acc[i][j] =
              __builtin_amdgcn_mfma_f32_16x16x32_bf16(af[i], bf[j], acc[i][j], 0, 0, 0);
    }
  }
#pragma unroll
  for (int j = 0; j < 4; ++j) {
    const int col = bn + wc + j * 16 + lr;
    const float bv = g.bias ? g.bias[col] : 0.0f;
#pragma unroll
    for (int i = 0; i < 2; ++i) {
#pragma unroll
      for (int ii = 0; ii < 4; ++ii) {
        const int row = bm + wr + i * 16 + lg * 4 + ii;
        float v = acc[i][j][ii] + bv;
        if (g.add) v += g.add[(size_t)row * g.N + col];
        if (g.relu) v = fmaxf(v, 0.0f);
        if (g.Cf) g.Cf[(size_t)row * g.N + col] = v;
        if (g.Cb) g.Cb[(size_t)row * g.N + col] = f2bf(v);
      }
    }
  }
}

// ---------------- decision gate, pass 1 (packed f32 MAC) --------------------
// grid (16 d-splits, B=4, 9 pairs), block 256. 64x64 outputs/block, 4x4 per
// thread. f32x2 accumulators per class (joined x+y at the end), b128 LDS
// reads. Targets v_pk_fma_f32 / v_pk_max_f32.
__global__ __launch_bounds__(256) void decision_part(
    const float* __restrict__ A1, const float* __restrict__ A0,
    const float* __restrict__ w2, float2* __restrict__ PART) {
  __shared__ float sA1[64][68];   // 64 rows x 64 d (f32x4-padded)
  __shared__ float sA0[64][68];
  __shared__ float sW0[64];       // class-0 weights for this 64-d chunk
  __shared__ float sW1[64];       // class-1
  const int ds = blockIdx.x;      // d range [ds*128, ds*128+128)
  const int b = blockIdx.y, pp = blockIdx.z;
  const int i = pp / 3, j = pp % 3;
  const int tid = threadIdx.x;
  const int tq = tid >> 4, tk = tid & 15;
  const float* a1base = A1 + ((size_t)(j * 4 + b) * 64) * 2048 + ds * 128;
  const float* a0base = A0 + ((size_t)(i * 4 + b) * 64) * 2048 + ds * 128;
  f32x2 acc0[4][4] = {};
  f32x2 acc1[4][4] = {};
  const f32x2 z2 = {0.f, 0.f};
  for (int c = 0; c < 2; ++c) {   // two 64-d chunks
    __syncthreads();
#pragma unroll
    for (int t = 0; t < 4; ++t) {
      const int row = t * 16 + tq;
      const int col = tk * 4;
      *(float4*)&sA1[row][col] =
          *(const float4*)(a1base + (size_t)row * 2048 + c * 64 + col);
      *(float4*)&sA0[row][col] =
          *(const float4*)(a0base + (size_t)row * 2048 + c * 64 + col);
    }
    if (tid < 32) {
      float4 wv = *(const float4*)(w2 + (size_t)(ds * 128 + c * 64 + tid * 2) * 2);
      sW0[tid * 2] = wv.x;     sW1[tid * 2] = wv.y;
      sW0[tid * 2 + 1] = wv.z; sW1[tid * 2 + 1] = wv.w;
    }
    __syncthreads();
#pragma unroll 2
    for (int s4 = 0; s4 < 16; ++s4) {   // 4 d per iteration (2 pairs)
      f32x2 a1lo[4], a1hi[4], a0lo[4], a0hi[4];
#pragma unroll
      for (int r = 0; r < 4; ++r) {
        float4 v1 = *(const float4*)&sA1[tq + 16 * r][s4 * 4];
        float4 v0 = *(const float4*)&sA0[tk + 16 * r][s4 * 4];
        a1lo[r] = f32x2{v1.x, v1.y}; a1hi[r] = f32x2{v1.z, v1.w};
        a0lo[r] = f32x2{v0.x, v0.y}; a0hi[r] = f32x2{v0.z, v0.w};
      }
      float4 w0v = *(const float4*)&sW0[s4 * 4];
      float4 w1v = *(const float4*)&sW1[s4 * 4];
      f32x2 w0lo = f32x2{w0v.x, w0v.y}, w0hi = f32x2{w0v.z, w0v.w};
      f32x2 w1lo = f32x2{w1v.x, w1v.y}, w1hi = f32x2{w1v.z, w1v.w};
#pragma unroll
      for (int qr = 0; qr < 4; ++qr)
#pragma unroll
        for (int kr = 0; kr < 4; ++kr) {
          f32x2 v = __builtin_elementwise_max(a1lo[qr] + a0lo[kr], z2);
          acc0[qr][kr] = __builtin_elementwise_fma(v, w0lo, acc0[qr][kr]);
          acc1[qr][kr] = __builtin_elementwise_fma(v, w1lo, acc1[qr][kr]);
          f32x2 u = __builtin_elementwise_max(a1hi[qr] + a0hi[kr], z2);
          acc0[qr][kr] = __builtin_elementwise_fma(u, w0hi, acc0[qr][kr]);
          acc1[qr][kr] = __builtin_elementwise_fma(u, w1hi, acc1[qr][kr]);
        }
    }
  }
  float2* outp = PART + (size_t)ds * 147456 + ((size_t)pp * 4 + b) * 4096;
#pragma unroll
  for (int qr = 0; qr < 4; ++qr)
#pragma unroll
    for (int kr = 0; kr < 4; ++kr) {
      float2 o;
      o.x = acc0[qr][kr].x + acc0[qr][kr].y;
      o.y = acc1[qr][kr].x + acc1[qr][kr].y;
      outp[(tq + 16 * qr) * 64 + (tk + 16 * kr)] = o;
    }
}

// ---------------- decision gate, pass 2: reduce + compare -------------------
__global__ __launch_bounds__(256) void decision_reduce(
    const float2* __restrict__ PART, const float* __restrict__ b2,
    float* __restrict__ DEC) {
  const int out = blockIdx.x * 256 + threadIdx.x;
  float acc0 = 0.f, acc1 = 0.f;
#pragma unroll
  for (int s = 0; s < 16; ++s) {
    float2 v = PART[(size_t)s * 147456 + out];
    acc0 += v.x;
    acc1 += v.y;
  }
  float l0 = acc0 + b2[0], l1 = acc1 + b2[1];
  DEC[out] = (l1 > l0) ? NEGV : 0.f;
}

// ---------------- MFMA attention (full barrier discipline) ------------------
__global__ __launch_bounds__(256) void attn_mfma(
    const unsigned short* __restrict__ Qa, const unsigned short* __restrict__ Ka,
    const unsigned short* __restrict__ Va, const float* __restrict__ DEC,
    const int* __restrict__ mask, unsigned short* __restrict__ O) {
  __shared__ __align__(16) char sm[49408];
  char* KsP = sm;
  char* Vt = sm + 24576;
  float* invs = (float*)(sm + 49152);

  const int h = blockIdx.x, b = blockIdx.y, i = blockIdx.z;
  const int tid = threadIdx.x;
  const int l = tid & 63, w = tid >> 6;
  const int l15 = l & 15, lg = l >> 4;

#pragma unroll
  for (int rep = 0; rep < 6; ++rep) {
    int flat = rep * 256 + tid;
    int key = flat >> 3, c8 = flat & 7;
    int j = key >> 6, kl = key & 63;
    const size_t rowoff = (((size_t)(j * 4 + b) * 64 + kl) * 1024) + h * 64 + c8 * 8;
    u16x8 kv = *(const u16x8*)(Ka + rowoff);
    *(u16x8*)(KsP + ((key * 128 + c8 * 16) ^ ((key & 7) << 4))) = kv;
    u16x8 vv = *(const u16x8*)(Va + rowoff);
#pragma unroll
    for (int jj = 0; jj < 8; ++jj) {
      int d = c8 * 8 + jj;
      *(unsigned short*)(Vt + ((d * 384 + key * 2) ^ ((d & 7) << 4))) = vv[jj];
    }
  }

  const int qg = w * 16 + l15;
  const unsigned short* qsrc =
      Qa + (((size_t)(i * 4 + b) * 64 + qg) * 1024) + h * 64 + lg * 8;
  short8 qf0 = *(const short8*)(qsrc);
  short8 qf1 = *(const short8*)(qsrc + 32);

  __syncthreads();  // (1)

  f32x4 s[12];
#pragma unroll
  for (int t = 0; t < 12; ++t) {
    const int key = t * 16 + l15;
    const int swz = (key & 7) << 4;
    short8 kf0 = *(const short8*)(KsP + ((key * 128 + 0 + lg * 16) ^ swz));
    short8 kf1 = *(const short8*)(KsP + ((key * 128 + 64 + lg * 16) ^ swz));
    f32x4 z = {0.f, 0.f, 0.f, 0.f};
    z = __builtin_amdgcn_mfma_f32_16x16x32_bf16(kf0, qf0, z, 0, 0, 0);
    z = __builtin_amdgcn_mfma_f32_16x16x32_bf16(kf1, qf1, z, 0, 0, 0);
    s[t] = z;
  }

  int mk[4][4];
#pragma unroll
  for (int t4 = 0; t4 < 4; ++t4)
#pragma unroll
    for (int r = 0; r < 4; ++r)
      mk[t4][r] = mask[((size_t)b * 64 + qg) * 64 + t4 * 16 + lg * 4 + r];

  float mx = -3.0e38f;
#pragma unroll
  for (int t = 0; t < 12; ++t) {
    const float* dbase =
        DEC + (((size_t)(i * 3 + (t >> 2)) * 4 + b) * 4096) + qg * 64;
#pragma unroll
    for (int r = 0; r < 4; ++r) {
      const int kl = (t & 3) * 16 + lg * 4 + r;
      float sv = s[t][r] * 0.125f + dbase[kl];
      if (mk[t & 3][r] == 0) sv = NEGV;
      s[t][r] = sv;
      mx = fmaxf(mx, sv);
    }
  }
  mx = fmaxf(mx, __shfl_xor(mx, 16));
  mx = fmaxf(mx, __shfl_xor(mx, 32));
  float sum = 0.f;
#pragma unroll
  for (int t = 0; t < 12; ++t)
#pragma unroll
    for (int r = 0; r < 4; ++r) {
      float p = __expf(s[t][r] - mx);
      s[t][r] = p;
      sum += p;
    }
  sum += __shfl_xor(sum, 16);
  sum += __shfl_xor(sum, 32);
  if (l < 16) invs[w * 16 + l] = 1.0f / sum;

  __syncthreads();  // (2)

  char* Pmy = KsP + w * 6144;
  const int pswz = (l15 & 7) << 4;

#pragma unroll
  for (int t = 0; t < 12; ++t)
#pragma unroll
    for (int r = 0; r < 4; ++r) {
      const int key = t * 16 + lg * 4 + r;
      *(unsigned short*)(Pmy + ((l15 * 384 + key * 2) ^ pswz)) = f2bf(s[t][r]);
    }
  __syncthreads();  // (3)

  f32x4 o[4] = {};
#pragma unroll
  for (int kc = 0; kc < 6; ++kc) {
    short8 pf = *(const short8*)(Pmy + ((l15 * 384 + kc * 64 + lg * 16) ^ pswz));
#pragma unroll
    for (int dt = 0; dt < 4; ++dt) {
      const int d = dt * 16 + l15;
      short8 vf = *(const short8*)(Vt + ((d * 384 + kc * 64 + lg * 16) ^ ((d & 7) << 4)));
      o[dt] = __builtin_amdgcn_mfma_f32_16x16x32_bf16(pf, vf, o[dt], 0, 0, 0);
    }
  }
  __syncthreads();  // (4)

#pragma unroll
  for (int t = 0; t < 12; ++t)
#pragma unroll
    for (int r = 0; r < 4; ++r) {
      const int key = t * 16 + lg * 4 + r;
      float p = s[t][r];
      float lo = p - bf2f(f2bf(p));
      *(unsigned short*)(Pmy + ((l15 * 384 + key * 2) ^ pswz)) = f2bf(lo);
    }
  __syncthreads();  // (5)

#pragma unroll
  for (int kc = 0; kc < 6; ++kc) {
    short8 pf = *(const short8*)(Pmy + ((l15 * 384 + kc * 64 + lg * 16) ^ pswz));
#pragma unroll
    for (int dt = 0; dt < 4; ++dt) {
      const int d = dt * 16 + l15;
      short8 vf = *(const short8*)(Vt + ((d * 384 + kc * 64 + lg * 16) ^ ((d & 7) << 4)));
      o[dt] = __builtin_amdgcn_mfma_f32_16x16x32_bf16(pf, vf, o[dt], 0, 0, 0);
    }
  }

#pragma unroll
  for (int dt = 0; dt < 4; ++dt)
#pragma unroll
    for (int r = 0; r < 4; ++r) {
      const int ql = lg * 4 + r;
      const float inv = invs[w * 16 + ql];
      const int d = dt * 16 + l15;
      O[(((size_t)(i * 4 + b) * 64 + w * 16 + ql) * 1024) + h * 64 + d] =
          f2bf(o[dt][r] * inv);
    }
}

// ---------------- layer norm over rows of 1024 ------------------------------
__global__ __launch_bounds__(256) void ln_kernel(const float* __restrict__ X,
                                                 const float* __restrict__ g,
                                                 const float* __restrict__ be,
                                                 float* __restrict__ Y,
                                                 unsigned short* __restrict__ Yb) {
  __shared__ float rs[8];
  int row = blockIdx.x, tid = threadIdx.x;
  const float* x = X + (size_t)row * 1024 + tid * 4;
  float4 v = *(const float4*)x;
  float s = v.x + v.y + v.z + v.w;
  float s2 = v.x * v.x + v.y * v.y + v.z * v.z + v.w * v.w;
#pragma unroll
  for (int off = 32; off > 0; off >>= 1) {
    s += __shfl_down(s, off);
    s2 += __shfl_down(s2, off);
  }
  int lane = tid & 63, wid = tid >> 6;
  if (lane == 0) { rs[wid * 2] = s; rs[wid * 2 + 1] = s2; }
  __syncthreads();
  if (tid == 0) {
    float aa = rs[0] + rs[2] + rs[4] + rs[6];
    float cc = rs[1] + rs[3] + rs[5] + rs[7];
    rs[0] = aa; rs[1] = cc;
  }
  __syncthreads();
  float mu = rs[0] * (1.0f / 1024.0f);
  float var = rs[1] * (1.0f / 1024.0f) - mu * mu;
  var = fmaxf(var, 0.f);
  float inv = 1.0f / sqrtf(var + 1e-6f);
  float4 gv = *(const float4*)(g + tid * 4);
  float4 bv = *(const float4*)(be + tid * 4);
  float4 o;
  o.x = (v.x - mu) * inv * gv.x + bv.x;
  o.y = (v.y - mu) * inv * gv.y + bv.y;
  o.z = (v.z - mu) * inv * gv.z + bv.z;
  o.w = (v.w - mu) * inv * gv.w + bv.w;
  *(float4*)(Y + (size_t)row * 1024 + tid * 4) = o;
  if (Yb) {
    u16x4 ob;
    ob.x = f2bf(o.x); ob.y = f2bf(o.y); ob.z = f2bf(o.z); ob.w = f2bf(o.w);
    *(u16x4*)(Yb + (size_t)row * 1024 + tid * 4) = ob;
  }
}

// ---------------- fused FFN2 k-split reduce + LN2 ---------------------------
// v = sum(P[0..3]) + bias + add  (identical arithmetic to old fsum), then LN.
__global__ __launch_bounds__(256) void fsum_ln(
    const float* __restrict__ P, const float* __restrict__ bias,
    const float* __restrict__ add, const float* __restrict__ g,
    const float* __restrict__ be, float* __restrict__ Y) {
  __shared__ float rs[8];
  int row = blockIdx.x, tid = threadIdx.x;
  const int c = tid * 4;
  const size_t o = (size_t)row * 1024 + c;
  float4 p0 = *(const float4*)(P + o);
  float4 p1 = *(const float4*)(P + 786432 + o);
  float4 p2 = *(const float4*)(P + 2 * 786432 + o);
  float4 p3 = *(const float4*)(P + 3 * 786432 + o);
  float4 bs = *(const float4*)(bias + c);
  float4 ad = *(const float4*)(add + o);
  float4 v;
  v.x = ((p0.x + p1.x) + (p2.x + p3.x)) + bs.x + ad.x;
  v.y = ((p0.y + p1.y) + (p2.y + p3.y)) + bs.y + ad.y;
  v.z = ((p0.z + p1.z) + (p2.z + p3.z)) + bs.z + ad.z;
  v.w = ((p0.w + p1.w) + (p2.w + p3.w)) + bs.w + ad.w;
  float s = v.x + v.y + v.z + v.w;
  float s2 = v.x * v.x + v.y * v.y + v.z * v.z + v.w * v.w;
#pragma unroll
  for (int off = 32; off > 0; off >>= 1) {
    s += __shfl_down(s, off);
    s2 += __shfl_down(s2, off);
  }
  int lane = tid & 63, wid = tid >> 6;
  if (lane == 0) { rs[wid * 2] = s; rs[wid * 2 + 1] = s2; }
  __syncthreads();
  if (tid == 0) {
    float aa = rs[0] + rs[2] + rs[4] + rs[6];
    float cc = rs[1] + rs[3] + rs[5] + rs[7];
    rs[0] = aa; rs[1] = cc;
  }
  __syncthreads();
  float mu = rs[0] * (1.0f / 1024.0f);
  float var = rs[1] * (1.0f / 1024.0f) - mu * mu;
  var = fmaxf(var, 0.f);
  float inv = 1.0f / sqrtf(var + 1e-6f);
  float4 gv = *(const float4*)(g + c);
  float4 bv = *(const float4*)(be + c);
  float4 r;
  r.x = (v.x - mu) * inv * gv.x + bv.x;
  r.y = (v.y - mu) * inv * gv.y + bv.y;
  r.z = (v.z - mu) * inv * gv.z + bv.z;
  r.w = (v.w - mu) * inv * gv.w + bv.w;
  *(float4*)(Y + o) = r;
}

// ---------------------------------------------------------------------------
extern "C" void kernel_launch(void* const* d_in, const int* in_sizes, int n_in,
                              void* d_out, int out_size, void* d_ws,
                              size_t ws_size, hipStream_t stream) {
  const float* in_t = (const float*)d_in[0];
  const float* in_a = (const float*)d_in[1];
  const float* in_v = (const float*)d_in[2];
  const int* mask = (const int*)d_in[3];
  const float* w_qs = (const float*)d_in[4];
  const float* w_ks = (const float*)d_in[5];
  const float* w_vs = (const float*)d_in[6];
  const float* w_ds0 = (const float*)d_in[7];
  const float* w_ds1 = (const float*)d_in[8];
  const float* dc_w1 = (const float*)d_in[9];
  const float* dc_b1 = (const float*)d_in[10];
  const float* dc_w2 = (const float*)d_in[11];
  const float* dc_b2 = (const float*)d_in[12];
  const float* w_fc = (const float*)d_in[13];
  const float* ln1_g = (const float*)d_in[14];
  const float* ln1_b = (const float*)d_in[15];
  const float* ffn_w1 = (const float*)d_in[16];
  const float* ffn_b1 = (const float*)d_in[17];
  const float* ffn_w2 = (const float*)d_in[18];
  const float* ffn_b2 = (const float*)d_in[19];
  const float* ln2_g = (const float*)d_in[20];
  const float* ln2_b = (const float*)d_in[21];
  float* out = (float*)d_out;

  char* p = (char*)d_ws;
  auto alloc = [&](size_t bytes) {
    char* r = p;
    p += (bytes + 255) & ~(size_t)255;
    return r;
  };
  unsigned short* WQS = (unsigned short*)alloc(1024 * 1024 * 2);
  unsigned short* WKS = (unsigned short*)alloc(1024 * 1024 * 2);
  unsigned short* WVS = (unsigned short*)alloc(1024 * 1024 * 2);
  unsigned short* WD0 = (unsigned short*)alloc(1024 * 1024 * 2);
  unsigned short* WD1 = (unsigned short*)alloc(1024 * 1024 * 2);
  unsigned short* WW1 = (unsigned short*)alloc((size_t)2048 * 2048 * 2);
  unsigned short* WFC = (unsigned short*)alloc(1024 * 1024 * 2);
  unsigned short* WF1 = (unsigned short*)alloc((size_t)4096 * 1024 * 2);
  unsigned short* WF2 = (unsigned short*)alloc((size_t)1024 * 4096 * 2);
  float* Xf = (float*)alloc((size_t)786432 * 4);
  unsigned short* Xb = (unsigned short*)alloc((size_t)786432 * 2);
  unsigned short* Qb = (unsigned short*)alloc((size_t)786432 * 2);
  unsigned short* Kb = (unsigned short*)alloc((size_t)786432 * 2);
  unsigned short* Vb = (unsigned short*)alloc((size_t)786432 * 2);
  unsigned short* D0b = (unsigned short*)alloc((size_t)786432 * 2);
  unsigned short* D1b = (unsigned short*)alloc((size_t)786432 * 2);
  float* DEC = (float*)alloc((size_t)147456 * 4);
  unsigned short* OATTb = (unsigned short*)alloc((size_t)786432 * 2);
  float2* PART = (float2*)alloc((size_t)16 * 147456 * 8);  // 18.9 MB partials
  float* FPART = (float*)PART;  // reused after decision for FFN2 k-split
  char* U = alloc((size_t)14155776);
  float* A0f = (float*)U;
  float* A1f = (float*)(U + (size_t)6291456);
  float* F2 = (float*)U;
  float* O1f = (float*)(U + (size_t)3145728);
  unsigned short* O1b = (unsigned short*)(U + (size_t)6291456);
  unsigned short* Hfb = (unsigned short*)(U + (size_t)7864320);

  dim3 blk(256);

  WtJobs jobs;
  int ts = 0;
  auto setjob = [&](int idx, const float* s, unsigned short* d, int K, int N) {
    jobs.j[idx].src = s; jobs.j[idx].dst = d;
    jobs.j[idx].K = K; jobs.j[idx].N = N; jobs.j[idx].tstart = ts;
    ts += (K / 32) * (N / 32);
  };
  setjob(0, w_qs, WQS, 1024, 1024);
  setjob(1, w_ks, WKS, 1024, 1024);
  setjob(2, w_vs, WVS, 1024, 1024);
  setjob(3, w_ds0, WD0, 1024, 1024);
  setjob(4, w_ds1, WD1, 1024, 1024);
  setjob(5, dc_w1, WW1, 2048, 2048);
  setjob(6, w_fc, WFC, 1024, 1024);
  setjob(7, ffn_w1, WF1, 1024, 4096);
  setjob(8, ffn_w2, WF2, 4096, 1024);
  wt_transpose<<<dim3(ts), blk, 0, stream>>>(jobs);

  concat3<<<dim3(768), blk, 0, stream>>>((const float4*)in_t,
                                         (const float4*)in_a,
                                         (const float4*)in_v,
                                         (float4*)Xf, (u16x4*)Xb);

  GemmBatch proj{};
  unsigned short* pouts[5] = {Qb, Kb, Vb, D0b, D1b};
  const unsigned short* pws[5] = {WQS, WKS, WVS, WD0, WD1};
  for (int z = 0; z < 5; ++z) {
    proj.op[z].A = Xb; proj.op[z].B = pws[z];
    proj.op[z].bias = nullptr; proj.op[z].add = nullptr;
    proj.op[z].Cf = nullptr; proj.op[z].Cb = pouts[z];
    proj.op[z].lda = 1024; proj.op[z].ldb = 1024;
    proj.op[z].N = 1024; proj.op[z].K = 1024; proj.op[z].relu = 0;
  }
  gemm_mfma<<<dim3(8, 12, 5), blk, 0, stream>>>(proj);

  GemmBatch pair{};
  pair.op[0].A = D0b; pair.op[0].B = WW1 + 1024;
  pair.op[0].bias = nullptr; pair.op[0].add = nullptr;
  pair.op[0].Cf = A0f; pair.op[0].Cb = nullptr;
  pair.op[0].lda = 1024; pair.op[0].ldb = 2048;
  pair.op[0].N = 2048; pair.op[0].K = 1024; pair.op[0].relu = 0;
  pair.op[1] = pair.op[0];
  pair.op[1].A = D1b; pair.op[1].B = WW1; pair.op[1].bias = dc_b1;
  pair.op[1].Cf = A1f;
  gemm_mfma<<<dim3(16, 12, 2), blk, 0, stream>>>(pair);

  decision_part<<<dim3(16, 4, 9), blk, 0, stream>>>(A1f, A0f, dc_w2, PART);
  decision_reduce<<<dim3(576), blk, 0, stream>>>(PART, dc_b2, DEC);

  attn_mfma<<<dim3(16, 4, 3), blk, 0, stream>>>(Qb, Kb, Vb, DEC, mask, OATTb);

  GemmBatch fc{};
  fc.op[0].A = OATTb; fc.op[0].B = WFC;
  fc.op[0].bias = nullptr; fc.op[0].add = Xf;
  fc.op[0].Cf = F2; fc.op[0].Cb = nullptr;
  fc.op[0].lda = 1024; fc.op[0].ldb = 1024;
  fc.op[0].N = 1024; fc.op[0].K = 1024; fc.op[0].relu = 0;
  gemm_mfma<<<dim3(8, 12, 1), blk, 0, stream>>>(fc);

  ln_kernel<<<dim3(768), blk, 0, stream>>>(F2, ln1_g, ln1_b, O1f, O1b);

  GemmBatch f1{};
  f1.op[0].A = O1b; f1.op[0].B = WF1;
  f1.op[0].bias = ffn_b1; f1.op[0].add = nullptr;
  f1.op[0].Cf = nullptr; f1.op[0].Cb = Hfb;
  f1.op[0].lda = 1024; f1.op[0].ldb = 1024;
  f1.op[0].N = 4096; f1.op[0].K = 1024; f1.op[0].relu = 1;
  gemm_mfma<<<dim3(32, 12, 1), blk, 0, stream>>>(f1);

  // FFN2 k-split x4: partials into FPART, then fused reduce+LN2
  GemmBatch f2{};
  for (int z = 0; z < 4; ++z) {
    f2.op[z].A = Hfb + (size_t)z * 1024;
    f2.op[z].B = WF2 + (size_t)z * 1024;
    f2.op[z].bias = nullptr; f2.op[z].add = nullptr;
    f2.op[z].Cf = FPART + (size_t)z * 786432; f2.op[z].Cb = nullptr;
    f2.op[z].lda = 4096; f2.op[z].ldb = 4096;
    f2.op[z].N = 1024; f2.op[z].K = 1024; f2.op[z].relu = 0;
  }
  gemm_mfma<<<dim3(8, 12, 4), blk, 0, stream>>>(f2);

  fsum_ln<<<dim3(768), blk, 0, stream>>>(FPART, ffn_b2, O1f, ln2_g, ln2_b, out);
}

// Round 8
// 178.779 us; speedup vs baseline: 5.3412x; 1.0376x over previous
//
#include <hip/hip_runtime.h>
#include <math.h>

// ---------------------------------------------------------------------------
// MMModel bf16-MFMA implementation. B=4, L=64, DM=1024, H=16, DK=DV=64,
// D=1024, DI=4096, nm=3. Row convention: row = (i*B + b)*L + l  (768 rows).
// ---------------------------------------------------------------------------

#define NEGV (-1000000000.0f)

typedef float f32x4 __attribute__((ext_vector_type(4)));
typedef short short8 __attribute__((ext_vector_type(8)));
typedef unsigned short u16x8 __attribute__((ext_vector_type(8)));
typedef unsigned short u16x4 __attribute__((ext_vector_type(4)));

typedef __attribute__((address_space(1))) const void glob_cv;
typedef __attribute__((address_space(3))) void lds_v;

static __device__ __forceinline__ unsigned short f2bf(float f) {
  unsigned u = __builtin_bit_cast(unsigned, f);
  u += 0x7fffu + ((u >> 16) & 1u);
  return (unsigned short)(u >> 16);
}
static __device__ __forceinline__ float bf2f(unsigned short h) {
  return __builtin_bit_cast(float, ((unsigned)h) << 16);
}

// async global->LDS, 16B per lane (linear dest = base + lane*16).
static __device__ __forceinline__ void gload16(const unsigned short* g,
                                               unsigned short* l) {
  __builtin_amdgcn_global_load_lds((glob_cv*)g, (lds_v*)l, 16, 0, 0);
}

// ---------------- concat inputs into Xf[768][1024] f32 + Xb bf16 ------------
__global__ __launch_bounds__(256) void concat3(const float4* __restrict__ t,
                                               const float4* __restrict__ a,
                                               const float4* __restrict__ v,
                                               float4* __restrict__ Xf,
                                               u16x4* __restrict__ Xb) {
  int id = blockIdx.x * 256 + threadIdx.x;  // 768*256 float4s
  int m = id >> 16;
  int off = id & 65535;
  const float4* s = (m == 0) ? t : (m == 1) ? a : v;
  float4 val = s[off];
  Xf[id] = val;
  u16x4 bb;
  bb.x = f2bf(val.x); bb.y = f2bf(val.y);
  bb.z = f2bf(val.z); bb.w = f2bf(val.w);
  Xb[id] = bb;
}

// ---------------- weight transpose + f32->bf16: dst[n][k] = src[k][n] -------
struct WtJob { const float* src; unsigned short* dst; int K, N, tstart; };
struct WtJobs { WtJob j[9]; };

__global__ __launch_bounds__(256) void wt_transpose(WtJobs jobs) {
  __shared__ float Ls[32][33];
  int ji = 0;
#pragma unroll
  for (int t = 1; t < 9; ++t)
    if ((int)blockIdx.x >= jobs.j[t].tstart) ji = t;
  const WtJob jb = jobs.j[ji];
  int local = blockIdx.x - jb.tstart;
  int ntx = jb.N >> 5;
  int tk = local / ntx, tn = local - tk * ntx;
  const int tid = threadIdx.x;
  const int r = tid >> 3, c = (tid & 7) * 4;
  float4 v = *(const float4*)(jb.src + (size_t)(tk * 32 + r) * jb.N + tn * 32 + c);
  Ls[r][c + 0] = v.x; Ls[r][c + 1] = v.y;
  Ls[r][c + 2] = v.z; Ls[r][c + 3] = v.w;
  __syncthreads();
  u16x4 o;
  o.x = f2bf(Ls[c + 0][r]);
  o.y = f2bf(Ls[c + 1][r]);
  o.z = f2bf(Ls[c + 2][r]);
  o.w = f2bf(Ls[c + 3][r]);
  *(u16x4*)(jb.dst + (size_t)(tn * 32 + r) * jb.K + tk * 32 + c) = o;
}

// ---------------- bf16 MFMA GEMM (64M x 128N tile, global_load_lds) ---------
struct GemmOp {
  const unsigned short* A;
  const unsigned short* B;   // Wt, row n, col k, stride ldb
  const float* bias;         // [N] or null
  const float* add;          // [768][N] f32 or null
  float* Cf;                 // or null
  unsigned short* Cb;        // or null
  int lda, ldb, N, K, relu;
};
struct GemmBatch { GemmOp op[5]; };

__global__ __launch_bounds__(256, 2) void gemm_mfma(GemmBatch batch) {
  const GemmOp g = batch.op[blockIdx.z];
  __shared__ unsigned short As[64 * 64];    // [m][k] linear
  __shared__ unsigned short Bs[128 * 64];   // [n][k] linear
  const int bm = blockIdx.y * 64, bn = blockIdx.x * 128;
  const int tid = threadIdx.x;
  const int l = tid & 63, w = tid >> 6;
  const int wr = (w >> 1) * 32, wc = (w & 1) * 64;
  const int lr = l & 15, lg = l >> 4;
  const int crow = l >> 3, ccol = (l & 7) * 8;  // within 8-row staging chunk
  f32x4 acc[2][4] = {};
  for (int k0 = 0; k0 < g.K; k0 += 64) {
    __syncthreads();
#pragma unroll
    for (int c = 0; c < 2; ++c) {           // A: 8 chunks of 8 rows
      const int ch = w * 2 + c;
      gload16(g.A + (size_t)(bm + ch * 8 + crow) * g.lda + k0 + ccol,
              &As[ch * 512 + l * 8]);
    }
#pragma unroll
    for (int c = 0; c < 4; ++c) {           // B: 16 chunks of 8 rows
      const int ch = w * 4 + c;
      gload16(g.B + (size_t)(bn + ch * 8 + crow) * g.ldb + k0 + ccol,
              &Bs[ch * 512 + l * 8]);
    }
    __syncthreads();
#pragma unroll
    for (int ks = 0; ks < 2; ++ks) {
      short8 af[2], bf[4];
#pragma unroll
      for (int i = 0; i < 2; ++i)
        af[i] = *(const short8*)&As[(wr + i * 16 + lr) * 64 + ks * 32 + lg * 8];
#pragma unroll
      for (int j = 0; j < 4; ++j)
        bf[j] = *(const short8*)&Bs[(wc + j * 16 + lr) * 64 + ks * 32 + lg * 8];
#pragma unroll
      for (int i = 0; i < 2; ++i)
#pragma unroll
        for (int j = 0; j < 4; ++j)
          acc[i][j] =
              __builtin_amdgcn_mfma_f32_16x16x32_bf16(af[i], bf[j], acc[i][j], 0, 0, 0);
    }
  }
#pragma unroll
  for (int j = 0; j < 4; ++j) {
    const int col = bn + wc + j * 16 + lr;
    const float bv = g.bias ? g.bias[col] : 0.0f;
#pragma unroll
    for (int i = 0; i < 2; ++i) {
#pragma unroll
      for (int ii = 0; ii < 4; ++ii) {
        const int row = bm + wr + i * 16 + lg * 4 + ii;
        float v = acc[i][j][ii] + bv;
        if (g.add) v += g.add[(size_t)row * g.N + col];
        if (g.relu) v = fmaxf(v, 0.0f);
        if (g.Cf) g.Cf[(size_t)row * g.N + col] = v;
        if (g.Cb) g.Cb[(size_t)row * g.N + col] = f2bf(v);
      }
    }
  }
}

// ---------------- decision gate, pass 1 v3 ----------------------------------
// Single-accumulator: PART[s][out] = sum_d relu(A1+A0) * (w2[d][1]-w2[d][0]).
// grid (32 d-splits x 64d, B=4, 9 pairs) = 1152 blocks; 4x4 outputs/thread.
// w2 read via uniform global address (scalar-load path), A1/A0 via LDS b128.
__global__ __launch_bounds__(256) void decision_part(
    const float* __restrict__ A1, const float* __restrict__ A0,
    const float* __restrict__ w2, float* __restrict__ PART) {
  __shared__ float sA1[64][68];   // 64 rows x 64 d
  __shared__ float sA0[64][68];
  const int ds = blockIdx.x;      // d range [ds*64, ds*64+64)
  const int b = blockIdx.y, pp = blockIdx.z;
  const int i = pp / 3, j = pp % 3;
  const int tid = threadIdx.x;
  const int tq = tid >> 4, tk = tid & 15;
  const float* a1base = A1 + ((size_t)(j * 4 + b) * 64) * 2048 + ds * 64;
  const float* a0base = A0 + ((size_t)(i * 4 + b) * 64) * 2048 + ds * 64;
#pragma unroll
  for (int t = 0; t < 4; ++t) {
    const int row = t * 16 + tq;
    const int col = tk * 4;
    *(float4*)&sA1[row][col] = *(const float4*)(a1base + (size_t)row * 2048 + col);
    *(float4*)&sA0[row][col] = *(const float4*)(a0base + (size_t)row * 2048 + col);
  }
  __syncthreads();
  float acc[4][4] = {};
  const float* wbase = w2 + (size_t)ds * 128;  // [64 d][2] for this block
#pragma unroll 4
  for (int s4 = 0; s4 < 16; ++s4) {   // 4 d per iteration
    // wd[dd] = w1-w0, block-uniform (scalar loads)
    float4 wv0 = *(const float4*)(wbase + s4 * 8);      // d0:(w0,w1) d1:(w0,w1)
    float4 wv1 = *(const float4*)(wbase + s4 * 8 + 4);  // d2,d3
    float wd0 = wv0.y - wv0.x, wd1 = wv0.w - wv0.z;
    float wd2 = wv1.y - wv1.x, wd3 = wv1.w - wv1.z;
    float4 a1v[4], a0v[4];
#pragma unroll
    for (int r = 0; r < 4; ++r) {
      a1v[r] = *(const float4*)&sA1[tq + 16 * r][s4 * 4];
      a0v[r] = *(const float4*)&sA0[tk + 16 * r][s4 * 4];
    }
#pragma unroll
    for (int qr = 0; qr < 4; ++qr)
#pragma unroll
      for (int kr = 0; kr < 4; ++kr) {
        float a = acc[qr][kr];
        a = fmaf(fmaxf(a1v[qr].x + a0v[kr].x, 0.f), wd0, a);
        a = fmaf(fmaxf(a1v[qr].y + a0v[kr].y, 0.f), wd1, a);
        a = fmaf(fmaxf(a1v[qr].z + a0v[kr].z, 0.f), wd2, a);
        a = fmaf(fmaxf(a1v[qr].w + a0v[kr].w, 0.f), wd3, a);
        acc[qr][kr] = a;
      }
  }
  float* outp = PART + (size_t)ds * 147456 + ((size_t)pp * 4 + b) * 4096;
#pragma unroll
  for (int qr = 0; qr < 4; ++qr)
#pragma unroll
    for (int kr = 0; kr < 4; ++kr)
      outp[(tq + 16 * qr) * 64 + (tk + 16 * kr)] = acc[qr][kr];
}

// ---------------- decision gate, pass 2: reduce + compare -------------------
// l1 > l0  <=>  sum_s PART[s] > b2[0] - b2[1]
__global__ __launch_bounds__(256) void decision_reduce(
    const float* __restrict__ PART, const float* __restrict__ b2,
    float* __restrict__ DEC) {
  const int out = blockIdx.x * 256 + threadIdx.x;
  float acc = 0.f;
#pragma unroll
  for (int s = 0; s < 32; ++s) acc += PART[(size_t)s * 147456 + out];
  const float thr = b2[0] - b2[1];
  DEC[out] = (acc > thr) ? NEGV : 0.f;
}

// ---------------- MFMA attention (full barrier discipline) ------------------
__global__ __launch_bounds__(256) void attn_mfma(
    const unsigned short* __restrict__ Qa, const unsigned short* __restrict__ Ka,
    const unsigned short* __restrict__ Va, const float* __restrict__ DEC,
    const int* __restrict__ mask, unsigned short* __restrict__ O) {
  __shared__ __align__(16) char sm[49408];
  char* KsP = sm;
  char* Vt = sm + 24576;
  float* invs = (float*)(sm + 49152);

  const int h = blockIdx.x, b = blockIdx.y, i = blockIdx.z;
  const int tid = threadIdx.x;
  const int l = tid & 63, w = tid >> 6;
  const int l15 = l & 15, lg = l >> 4;

#pragma unroll
  for (int rep = 0; rep < 6; ++rep) {
    int flat = rep * 256 + tid;
    int key = flat >> 3, c8 = flat & 7;
    int j = key >> 6, kl = key & 63;
    const size_t rowoff = (((size_t)(j * 4 + b) * 64 + kl) * 1024) + h * 64 + c8 * 8;
    u16x8 kv = *(const u16x8*)(Ka + rowoff);
    *(u16x8*)(KsP + ((key * 128 + c8 * 16) ^ ((key & 7) << 4))) = kv;
    u16x8 vv = *(const u16x8*)(Va + rowoff);
#pragma unroll
    for (int jj = 0; jj < 8; ++jj) {
      int d = c8 * 8 + jj;
      *(unsigned short*)(Vt + ((d * 384 + key * 2) ^ ((d & 7) << 4))) = vv[jj];
    }
  }

  const int qg = w * 16 + l15;
  const unsigned short* qsrc =
      Qa + (((size_t)(i * 4 + b) * 64 + qg) * 1024) + h * 64 + lg * 8;
  short8 qf0 = *(const short8*)(qsrc);
  short8 qf1 = *(const short8*)(qsrc + 32);

  __syncthreads();  // (1)

  f32x4 s[12];
#pragma unroll
  for (int t = 0; t < 12; ++t) {
    const int key = t * 16 + l15;
    const int swz = (key & 7) << 4;
    short8 kf0 = *(const short8*)(KsP + ((key * 128 + 0 + lg * 16) ^ swz));
    short8 kf1 = *(const short8*)(KsP + ((key * 128 + 64 + lg * 16) ^ swz));
    f32x4 z = {0.f, 0.f, 0.f, 0.f};
    z = __builtin_amdgcn_mfma_f32_16x16x32_bf16(kf0, qf0, z, 0, 0, 0);
    z = __builtin_amdgcn_mfma_f32_16x16x32_bf16(kf1, qf1, z, 0, 0, 0);
    s[t] = z;
  }

  int mk[4][4];
#pragma unroll
  for (int t4 = 0; t4 < 4; ++t4)
#pragma unroll
    for (int r = 0; r < 4; ++r)
      mk[t4][r] = mask[((size_t)b * 64 + qg) * 64 + t4 * 16 + lg * 4 + r];

  float mx = -3.0e38f;
#pragma unroll
  for (int t = 0; t < 12; ++t) {
    const float* dbase =
        DEC + (((size_t)(i * 3 + (t >> 2)) * 4 + b) * 4096) + qg * 64;
#pragma unroll
    for (int r = 0; r < 4; ++r) {
      const int kl = (t & 3) * 16 + lg * 4 + r;
      float sv = s[t][r] * 0.125f + dbase[kl];
      if (mk[t & 3][r] == 0) sv = NEGV;
      s[t][r] = sv;
      mx = fmaxf(mx, sv);
    }
  }
  mx = fmaxf(mx, __shfl_xor(mx, 16));
  mx = fmaxf(mx, __shfl_xor(mx, 32));
  float sum = 0.f;
#pragma unroll
  for (int t = 0; t < 12; ++t)
#pragma unroll
    for (int r = 0; r < 4; ++r) {
      float p = __expf(s[t][r] - mx);
      s[t][r] = p;
      sum += p;
    }
  sum += __shfl_xor(sum, 16);
  sum += __shfl_xor(sum, 32);
  if (l < 16) invs[w * 16 + l] = 1.0f / sum;

  __syncthreads();  // (2)

  char* Pmy = KsP + w * 6144;
  const int pswz = (l15 & 7) << 4;

#pragma unroll
  for (int t = 0; t < 12; ++t)
#pragma unroll
    for (int r = 0; r < 4; ++r) {
      const int key = t * 16 + lg * 4 + r;
      *(unsigned short*)(Pmy + ((l15 * 384 + key * 2) ^ pswz)) = f2bf(s[t][r]);
    }
  __syncthreads();  // (3)

  f32x4 o[4] = {};
#pragma unroll
  for (int kc = 0; kc < 6; ++kc) {
    short8 pf = *(const short8*)(Pmy + ((l15 * 384 + kc * 64 + lg * 16) ^ pswz));
#pragma unroll
    for (int dt = 0; dt < 4; ++dt) {
      const int d = dt * 16 + l15;
      short8 vf = *(const short8*)(Vt + ((d * 384 + kc * 64 + lg * 16) ^ ((d & 7) << 4)));
      o[dt] = __builtin_amdgcn_mfma_f32_16x16x32_bf16(pf, vf, o[dt], 0, 0, 0);
    }
  }
  __syncthreads();  // (4)

#pragma unroll
  for (int t = 0; t < 12; ++t)
#pragma unroll
    for (int r = 0; r < 4; ++r) {
      const int key = t * 16 + lg * 4 + r;
      float p = s[t][r];
      float lo = p - bf2f(f2bf(p));
      *(unsigned short*)(Pmy + ((l15 * 384 + key * 2) ^ pswz)) = f2bf(lo);
    }
  __syncthreads();  // (5)

#pragma unroll
  for (int kc = 0; kc < 6; ++kc) {
    short8 pf = *(const short8*)(Pmy + ((l15 * 384 + kc * 64 + lg * 16) ^ pswz));
#pragma unroll
    for (int dt = 0; dt < 4; ++dt) {
      const int d = dt * 16 + l15;
      short8 vf = *(const short8*)(Vt + ((d * 384 + kc * 64 + lg * 16) ^ ((d & 7) << 4)));
      o[dt] = __builtin_amdgcn_mfma_f32_16x16x32_bf16(pf, vf, o[dt], 0, 0, 0);
    }
  }

#pragma unroll
  for (int dt = 0; dt < 4; ++dt)
#pragma unroll
    for (int r = 0; r < 4; ++r) {
      const int ql = lg * 4 + r;
      const float inv = invs[w * 16 + ql];
      const int d = dt * 16 + l15;
      O[(((size_t)(i * 4 + b) * 64 + w * 16 + ql) * 1024) + h * 64 + d] =
          f2bf(o[dt][r] * inv);
    }
}

// ---------------- layer norm over rows of 1024 ------------------------------
__global__ __launch_bounds__(256) void ln_kernel(const float* __restrict__ X,
                                                 const float* __restrict__ g,
                                                 const float* __restrict__ be,
                                                 float* __restrict__ Y,
                                                 unsigned short* __restrict__ Yb) {
  __shared__ float rs[8];
  int row = blockIdx.x, tid = threadIdx.x;
  const float* x = X + (size_t)row * 1024 + tid * 4;
  float4 v = *(const float4*)x;
  float s = v.x + v.y + v.z + v.w;
  float s2 = v.x * v.x + v.y * v.y + v.z * v.z + v.w * v.w;
#pragma unroll
  for (int off = 32; off > 0; off >>= 1) {
    s += __shfl_down(s, off);
    s2 += __shfl_down(s2, off);
  }
  int lane = tid & 63, wid = tid >> 6;
  if (lane == 0) { rs[wid * 2] = s; rs[wid * 2 + 1] = s2; }
  __syncthreads();
  if (tid == 0) {
    float aa = rs[0] + rs[2] + rs[4] + rs[6];
    float cc = rs[1] + rs[3] + rs[5] + rs[7];
    rs[0] = aa; rs[1] = cc;
  }
  __syncthreads();
  float mu = rs[0] * (1.0f / 1024.0f);
  float var = rs[1] * (1.0f / 1024.0f) - mu * mu;
  var = fmaxf(var, 0.f);
  float inv = 1.0f / sqrtf(var + 1e-6f);
  float4 gv = *(const float4*)(g + tid * 4);
  float4 bv = *(const float4*)(be + tid * 4);
  float4 o;
  o.x = (v.x - mu) * inv * gv.x + bv.x;
  o.y = (v.y - mu) * inv * gv.y + bv.y;
  o.z = (v.z - mu) * inv * gv.z + bv.z;
  o.w = (v.w - mu) * inv * gv.w + bv.w;
  *(float4*)(Y + (size_t)row * 1024 + tid * 4) = o;
  if (Yb) {
    u16x4 ob;
    ob.x = f2bf(o.x); ob.y = f2bf(o.y); ob.z = f2bf(o.z); ob.w = f2bf(o.w);
    *(u16x4*)(Yb + (size_t)row * 1024 + tid * 4) = ob;
  }
}

// ---------------- fused FFN2 k-split reduce + LN2 ---------------------------
__global__ __launch_bounds__(256) void fsum_ln(
    const float* __restrict__ P, const float* __restrict__ bias,
    const float* __restrict__ add, const float* __restrict__ g,
    const float* __restrict__ be, float* __restrict__ Y) {
  __shared__ float rs[8];
  int row = blockIdx.x, tid = threadIdx.x;
  const int c = tid * 4;
  const size_t o = (size_t)row * 1024 + c;
  float4 p0 = *(const float4*)(P + o);
  float4 p1 = *(const float4*)(P + 786432 + o);
  float4 p2 = *(const float4*)(P + 2 * 786432 + o);
  float4 p3 = *(const float4*)(P + 3 * 786432 + o);
  float4 bs = *(const float4*)(bias + c);
  float4 ad = *(const float4*)(add + o);
  float4 v;
  v.x = ((p0.x + p1.x) + (p2.x + p3.x)) + bs.x + ad.x;
  v.y = ((p0.y + p1.y) + (p2.y + p3.y)) + bs.y + ad.y;
  v.z = ((p0.z + p1.z) + (p2.z + p3.z)) + bs.z + ad.z;
  v.w = ((p0.w + p1.w) + (p2.w + p3.w)) + bs.w + ad.w;
  float s = v.x + v.y + v.z + v.w;
  float s2 = v.x * v.x + v.y * v.y + v.z * v.z + v.w * v.w;
#pragma unroll
  for (int off = 32; off > 0; off >>= 1) {
    s += __shfl_down(s, off);
    s2 += __shfl_down(s2, off);
  }
  int lane = tid & 63, wid = tid >> 6;
  if (lane == 0) { rs[wid * 2] = s; rs[wid * 2 + 1] = s2; }
  __syncthreads();
  if (tid == 0) {
    float aa = rs[0] + rs[2] + rs[4] + rs[6];
    float cc = rs[1] + rs[3] + rs[5] + rs[7];
    rs[0] = aa; rs[1] = cc;
  }
  __syncthreads();
  float mu = rs[0] * (1.0f / 1024.0f);
  float var = rs[1] * (1.0f / 1024.0f) - mu * mu;
  var = fmaxf(var, 0.f);
  float inv = 1.0f / sqrtf(var + 1e-6f);
  float4 gv = *(const float4*)(g + c);
  float4 bv = *(const float4*)(be + c);
  float4 r;
  r.x = (v.x - mu) * inv * gv.x + bv.x;
  r.y = (v.y - mu) * inv * gv.y + bv.y;
  r.z = (v.z - mu) * inv * gv.z + bv.z;
  r.w = (v.w - mu) * inv * gv.w + bv.w;
  *(float4*)(Y + o) = r;
}

// ---------------------------------------------------------------------------
extern "C" void kernel_launch(void* const* d_in, const int* in_sizes, int n_in,
                              void* d_out, int out_size, void* d_ws,
                              size_t ws_size, hipStream_t stream) {
  const float* in_t = (const float*)d_in[0];
  const float* in_a = (const float*)d_in[1];
  const float* in_v = (const float*)d_in[2];
  const int* mask = (const int*)d_in[3];
  const float* w_qs = (const float*)d_in[4];
  const float* w_ks = (const float*)d_in[5];
  const float* w_vs = (const float*)d_in[6];
  const float* w_ds0 = (const float*)d_in[7];
  const float* w_ds1 = (const float*)d_in[8];
  const float* dc_w1 = (const float*)d_in[9];
  const float* dc_b1 = (const float*)d_in[10];
  const float* dc_w2 = (const float*)d_in[11];
  const float* dc_b2 = (const float*)d_in[12];
  const float* w_fc = (const float*)d_in[13];
  const float* ln1_g = (const float*)d_in[14];
  const float* ln1_b = (const float*)d_in[15];
  const float* ffn_w1 = (const float*)d_in[16];
  const float* ffn_b1 = (const float*)d_in[17];
  const float* ffn_w2 = (const float*)d_in[18];
  const float* ffn_b2 = (const float*)d_in[19];
  const float* ln2_g = (const float*)d_in[20];
  const float* ln2_b = (const float*)d_in[21];
  float* out = (float*)d_out;

  char* p = (char*)d_ws;
  auto alloc = [&](size_t bytes) {
    char* r = p;
    p += (bytes + 255) & ~(size_t)255;
    return r;
  };
  unsigned short* WQS = (unsigned short*)alloc(1024 * 1024 * 2);
  unsigned short* WKS = (unsigned short*)alloc(1024 * 1024 * 2);
  unsigned short* WVS = (unsigned short*)alloc(1024 * 1024 * 2);
  unsigned short* WD0 = (unsigned short*)alloc(1024 * 1024 * 2);
  unsigned short* WD1 = (unsigned short*)alloc(1024 * 1024 * 2);
  unsigned short* WW1 = (unsigned short*)alloc((size_t)2048 * 2048 * 2);
  unsigned short* WFC = (unsigned short*)alloc(1024 * 1024 * 2);
  unsigned short* WF1 = (unsigned short*)alloc((size_t)4096 * 1024 * 2);
  unsigned short* WF2 = (unsigned short*)alloc((size_t)1024 * 4096 * 2);
  float* Xf = (float*)alloc((size_t)786432 * 4);
  unsigned short* Xb = (unsigned short*)alloc((size_t)786432 * 2);
  unsigned short* Qb = (unsigned short*)alloc((size_t)786432 * 2);
  unsigned short* Kb = (unsigned short*)alloc((size_t)786432 * 2);
  unsigned short* Vb = (unsigned short*)alloc((size_t)786432 * 2);
  unsigned short* D0b = (unsigned short*)alloc((size_t)786432 * 2);
  unsigned short* D1b = (unsigned short*)alloc((size_t)786432 * 2);
  float* DEC = (float*)alloc((size_t)147456 * 4);
  unsigned short* OATTb = (unsigned short*)alloc((size_t)786432 * 2);
  float* PART = (float*)alloc((size_t)32 * 147456 * 4);  // 18.9 MB partials
  float* FPART = PART;  // reused after decision for FFN2 k-split
  char* U = alloc((size_t)14155776);
  float* A0f = (float*)U;
  float* A1f = (float*)(U + (size_t)6291456);
  float* F2 = (float*)U;
  float* O1f = (float*)(U + (size_t)3145728);
  unsigned short* O1b = (unsigned short*)(U + (size_t)6291456);
  unsigned short* Hfb = (unsigned short*)(U + (size_t)7864320);

  dim3 blk(256);

  WtJobs jobs;
  int ts = 0;
  auto setjob = [&](int idx, const float* s, unsigned short* d, int K, int N) {
    jobs.j[idx].src = s; jobs.j[idx].dst = d;
    jobs.j[idx].K = K; jobs.j[idx].N = N; jobs.j[idx].tstart = ts;
    ts += (K / 32) * (N / 32);
  };
  setjob(0, w_qs, WQS, 1024, 1024);
  setjob(1, w_ks, WKS, 1024, 1024);
  setjob(2, w_vs, WVS, 1024, 1024);
  setjob(3, w_ds0, WD0, 1024, 1024);
  setjob(4, w_ds1, WD1, 1024, 1024);
  setjob(5, dc_w1, WW1, 2048, 2048);
  setjob(6, w_fc, WFC, 1024, 1024);
  setjob(7, ffn_w1, WF1, 1024, 4096);
  setjob(8, ffn_w2, WF2, 4096, 1024);
  wt_transpose<<<dim3(ts), blk, 0, stream>>>(jobs);

  concat3<<<dim3(768), blk, 0, stream>>>((const float4*)in_t,
                                         (const float4*)in_a,
                                         (const float4*)in_v,
                                         (float4*)Xf, (u16x4*)Xb);

  GemmBatch proj{};
  unsigned short* pouts[5] = {Qb, Kb, Vb, D0b, D1b};
  const unsigned short* pws[5] = {WQS, WKS, WVS, WD0, WD1};
  for (int z = 0; z < 5; ++z) {
    proj.op[z].A = Xb; proj.op[z].B = pws[z];
    proj.op[z].bias = nullptr; proj.op[z].add = nullptr;
    proj.op[z].Cf = nullptr; proj.op[z].Cb = pouts[z];
    proj.op[z].lda = 1024; proj.op[z].ldb = 1024;
    proj.op[z].N = 1024; proj.op[z].K = 1024; proj.op[z].relu = 0;
  }
  gemm_mfma<<<dim3(8, 12, 5), blk, 0, stream>>>(proj);

  GemmBatch pair{};
  pair.op[0].A = D0b; pair.op[0].B = WW1 + 1024;
  pair.op[0].bias = nullptr; pair.op[0].add = nullptr;
  pair.op[0].Cf = A0f; pair.op[0].Cb = nullptr;
  pair.op[0].lda = 1024; pair.op[0].ldb = 2048;
  pair.op[0].N = 2048; pair.op[0].K = 1024; pair.op[0].relu = 0;
  pair.op[1] = pair.op[0];
  pair.op[1].A = D1b; pair.op[1].B = WW1; pair.op[1].bias = dc_b1;
  pair.op[1].Cf = A1f;
  gemm_mfma<<<dim3(16, 12, 2), blk, 0, stream>>>(pair);

  decision_part<<<dim3(32, 4, 9), blk, 0, stream>>>(A1f, A0f, dc_w2, PART);
  decision_reduce<<<dim3(576), blk, 0, stream>>>(PART, dc_b2, DEC);

  attn_mfma<<<dim3(16, 4, 3), blk, 0, stream>>>(Qb, Kb, Vb, DEC, mask, OATTb);

  GemmBatch fc{};
  fc.op[0].A = OATTb; fc.op[0].B = WFC;
  fc.op[0].bias = nullptr; fc.op[0].add = Xf;
  fc.op[0].Cf = F2; fc.op[0].Cb = nullptr;
  fc.op[0].lda = 1024; fc.op[0].ldb = 1024;
  fc.op[0].N = 1024; fc.op[0].K = 1024; fc.op[0].relu = 0;
  gemm_mfma<<<dim3(8, 12, 1), blk, 0, stream>>>(fc);

  ln_kernel<<<dim3(768), blk, 0, stream>>>(F2, ln1_g, ln1_b, O1f, O1b);

  GemmBatch f1{};
  f1.op[0].A = O1b; f1.op[0].B = WF1;
  f1.op[0].bias = ffn_b1; f1.op[0].add = nullptr;
  f1.op[0].Cf = nullptr; f1.op[0].Cb = Hfb;
  f1.op[0].lda = 1024; f1.op[0].ldb = 1024;
  f1.op[0].N = 4096; f1.op[0].K = 1024; f1.op[0].relu = 1;
  gemm_mfma<<<dim3(32, 12, 1), blk, 0, stream>>>(f1);

  // FFN2 k-split x4: partials into FPART, then fused reduce+LN2
  GemmBatch f2{};
  for (int z = 0; z < 4; ++z) {
    f2.op[z].A = Hfb + (size_t)z * 1024;
    f2.op[z].B = WF2 + (size_t)z * 1024;
    f2.op[z].bias = nullptr; f2.op[z].add = nullptr;
    f2.op[z].Cf = FPART + (size_t)z * 786432; f2.op[z].Cb = nullptr;
    f2.op[z].lda = 4096; f2.op[z].ldb = 4096;
    f2.op[z].N = 1024; f2.op[z].K = 1024; f2.op[z].relu = 0;
  }
  gemm_mfma<<<dim3(8, 12, 4), blk, 0, stream>>>(f2);

  fsum_ln<<<dim3(768), blk, 0, stream>>>(FPART, ffn_b2, O1f, ln2_g, ln2_b, out);
}